// Round 11
// baseline (563.426 us; speedup 1.0000x reference)
//
#include <hip/hip_runtime.h>
#include <hip/hip_bf16.h>

// ---------------------------------------------------------------------------
// mv3Dunet_down_text_cmsa forward. Round 11: conv tap-loop FULLY UNROLLED
// (compile-time taps -> compiler-scheduled counted waitcnt pipelining),
// launch_bounds(256,2) for VGPR headroom (r10's (256,3) silently serialized
// the hand pipeline at 72 VGPRs). conv2's bf16 chunk-major transpose fused
// into conv1's BN-apply. Tail otherwise identical to round 10.
// ---------------------------------------------------------------------------

using bf16x8 = __attribute__((ext_vector_type(8))) short;
using f32x4  = __attribute__((ext_vector_type(4))) float;

__device__ __forceinline__ unsigned short f2bf(float f) {
    unsigned int u = __float_as_uint(f);
    u += 0x7FFFu + ((u >> 16) & 1u);
    return (unsigned short)(u >> 16);
}

// in-place softmax over s[0..len) using one wave's 64 lanes
__device__ __forceinline__ void softseg(float* s, int len, int lane) {
    float m = -3.4e38f;
    for (int j = lane; j < len; j += 64) m = fmaxf(m, s[j]);
    for (int sh = 32; sh; sh >>= 1) m = fmaxf(m, __shfl_xor(m, sh));
    float sum = 0.f;
    for (int j = lane; j < len; j += 64) { float e = expf(s[j] - m); s[j] = e; sum += e; }
    for (int sh = 32; sh; sh >>= 1) sum += __shfl_xor(sum, sh);
    float inv = 1.f / sum;
    for (int j = lane; j < len; j += 64) s[j] *= inv;
}

// ---------------- X -> chunk-major bf16: xt[b][g][208][72] ----------------
__global__ void k_xt_c(const float* __restrict__ x, unsigned short* __restrict__ xt,
                       int IC, int G) {
    int b = blockIdx.y;
    int tot = G * 208 * 36;                  // uint writes
    int idx = blockIdx.x * 256 + threadIdx.x;
    if (idx >= tot) return;
    int g = idx / (208 * 36); int r = idx - g * 208 * 36;
    int s = r / 36, cp = r - s * 36;
    int cc = cp * 2;
    int ic = g * 64 + cc;
    unsigned int lo = 0, hi = 0;
    if (s < 196 && cc < 64 && ic < IC)         lo = f2bf(x[((size_t)b * IC + ic) * 196 + s]);
    if (s < 196 && cc + 1 < 64 && ic + 1 < IC) hi = f2bf(x[((size_t)b * IC + ic + 1) * 196 + s]);
    ((unsigned int*)xt)[(size_t)b * tot + idx] = lo | (hi << 16);
}

// ---------------- weight pack: w[oc][ic][27] f32 -> wp[t][oc][ic] bf16 ------
__global__ void k_wpack(const float* __restrict__ w, unsigned short* __restrict__ wp,
                        int IC) {
    int nc = IC >> 3;
    int idx = blockIdx.x * 256 + threadIdx.x;
    if (idx >= 27 * 128 * nc) return;
    int c = idx % nc; int r = idx / nc; int oc = r & 127; int t = r >> 7;
    const float* ws = w + ((size_t)oc * IC + c * 8) * 27 + t;
    unsigned int o0 = f2bf(ws[0])   | ((unsigned int)f2bf(ws[27])  << 16);
    unsigned int o1 = f2bf(ws[54])  | ((unsigned int)f2bf(ws[81])  << 16);
    unsigned int o2 = f2bf(ws[108]) | ((unsigned int)f2bf(ws[135]) << 16);
    unsigned int o3 = f2bf(ws[162]) | ((unsigned int)f2bf(ws[189]) << 16);
    uint4 v; v.x = o0; v.y = o1; v.z = o2; v.w = o3;
    ((uint4*)wp)[idx] = v;
}

// ---------------- MFMA conv, ic-chunk blocks, FULLY UNROLLED taps -----------
// Block = (g ic-chunk, nh N-slice of NT*16 oc, mh m-half, b).
// LDS = one 208x72 bf16 chunk. #pragma unroll over 27 taps: compile-time
// kd/kh/kw and literal B offsets -> compiler emits counted-waitcnt pipeline.
template <int IC, int G, int NT, int NH>
__global__ __launch_bounds__(256, 2) void k_convchunk3(
    const unsigned short* __restrict__ xt, const unsigned short* __restrict__ wp,
    float* __restrict__ part) {
    __shared__ unsigned short xs[208 * 72];
    const int tid = threadIdx.x;
    const int bx = blockIdx.x, b = blockIdx.y;
    const int mh = bx & 1;
    const int nh = (bx >> 1) % NH;
    const int g  = (bx >> 1) / NH;

    {
        const bf16x8* s8 = (const bf16x8*)(xt + ((size_t)b * G + g) * (208 * 72));
        bf16x8* d8 = (bf16x8*)xs;
        for (int c = tid; c < 208 * 72 / 8; c += 256) d8[c] = s8[c];
    }
    __syncthreads();

    const int lane = tid & 63, wv = tid >> 6;
    const int a = lane & 15, kg = lane >> 4;

    int md[2], mhh[2], mw[2];
#pragma unroll
    for (int i = 0; i < 2; ++i) {
        int m = (mh * 8 + wv * 2 + i) * 16 + a;
        md[i] = m / 49; int rr = m - md[i] * 49;
        mhh[i] = rr / 7; mw[i] = rr - mhh[i] * 7;
    }

    f32x4 acc[2][NT];
#pragma unroll
    for (int i = 0; i < 2; ++i)
#pragma unroll
        for (int nt = 0; nt < NT; ++nt) acc[i][nt] = (f32x4){0.f, 0.f, 0.f, 0.f};

    const bf16x8 zv = {0, 0, 0, 0, 0, 0, 0, 0};
    const unsigned short* wbase = wp + ((size_t)(nh * NT * 16 + a)) * IC + g * 64 + kg * 8;

#pragma unroll
    for (int t = 0; t < 27; ++t) {
        const int kd = t / 9, kh = (t / 3) % 3, kw = t % 3;   // compile-time
        int rsrc[2]; bool ok[2];
#pragma unroll
        for (int i = 0; i < 2; ++i) {
            int d2 = md[i] + kd - 1, h2 = mhh[i] + kh - 1, w2 = mw[i] + kw - 1;
            ok[i] = ((unsigned)d2 < 4u) & ((unsigned)h2 < 7u) & ((unsigned)w2 < 7u);
            rsrc[i] = ok[i] ? (d2 * 49 + h2 * 7 + w2) : 0;
        }
        bf16x8 A[2][2];
#pragma unroll
        for (int kk = 0; kk < 2; ++kk)
#pragma unroll
            for (int i = 0; i < 2; ++i) {
                bf16x8 v = *(const bf16x8*)(xs + rsrc[i] * 72 + kk * 32 + kg * 8);
                A[kk][i] = ok[i] ? v : zv;
            }
        const unsigned short* wr = wbase + (size_t)t * 128 * IC;
#pragma unroll
        for (int kk = 0; kk < 2; ++kk)
#pragma unroll
            for (int nt = 0; nt < NT; ++nt) {
                bf16x8 B = *(const bf16x8*)(wr + (size_t)nt * 16 * IC + kk * 32);
#pragma unroll
                for (int i = 0; i < 2; ++i)
                    acc[i][nt] = __builtin_amdgcn_mfma_f32_16x16x32_bf16(
                        A[kk][i], B, acc[i][nt], 0, 0, 0);
            }
    }

    float* dst = part + ((size_t)g * 32 + b) * (128 * 196);
#pragma unroll
    for (int i = 0; i < 2; ++i) {
        int m0 = (mh * 8 + wv * 2 + i) * 16 + kg * 4;
        if (m0 < 196) {
#pragma unroll
            for (int nt = 0; nt < NT; ++nt) {
                int oc = nh * NT * 16 + nt * 16 + a;
                *(f32x4*)(dst + (size_t)oc * 196 + m0) = acc[i][nt];
            }
        }
    }
}

// sum G partials
template <int G>
__global__ void k_reduceG(const float* __restrict__ part, float* __restrict__ y, int n) {
    int i = blockIdx.x * blockDim.x + threadIdx.x;
    if (i < n) {
        float s = 0.f;
#pragma unroll
        for (int g = 0; g < G; ++g) s += part[(size_t)g * n + i];
        y[i] = s;
    }
}

// ---------------- transpose of 8 [196,196] matrices ----------------
struct P8 { const float* p[8]; };
__global__ void k_transpose8(P8 ws_in, float* __restrict__ wt) {
    int i = blockIdx.x, m = blockIdx.y;
    const float* w = ws_in.p[m];
    float* o = wt + (size_t)m * 38416;
    for (int t = threadIdx.x; t < 196; t += blockDim.x)
        o[(size_t)i * 196 + t] = w[(size_t)t * 196 + i];
}

// ---------------- BN ----------------
__global__ void k_bn_stats(const float* __restrict__ y, float* __restrict__ stats,
                           int C) {
    int ch = blockIdx.x; int tid = threadIdx.x;
    float s = 0.f, s2 = 0.f;
    for (int b = 0; b < 32; ++b) {
        const float* p = &y[(size_t)(b * C + ch) * 196];
        for (int i = tid; i < 196; i += 256) { float v = p[i]; s += v; s2 += v * v; }
    }
    __shared__ float r1[4], r2[4];
    for (int sh = 32; sh; sh >>= 1) { s += __shfl_xor(s, sh); s2 += __shfl_xor(s2, sh); }
    if ((tid & 63) == 0) { r1[tid >> 6] = s; r2[tid >> 6] = s2; }
    __syncthreads();
    if (tid == 0) {
        float S = r1[0] + r1[1] + r1[2] + r1[3];
        float S2 = r2[0] + r2[1] + r2[2] + r2[3];
        float m = S / 6272.f;
        float v = S2 / 6272.f - m * m;
        stats[2 * ch] = m;
        stats[2 * ch + 1] = rsqrtf(v + 1e-5f);
    }
}

// optional fT (transposed twin) and xtc (chunk-major bf16 for next conv)
__global__ void k_bn_apply_relu(float* __restrict__ y, const float* __restrict__ stats,
                                const float* __restrict__ g, const float* __restrict__ be,
                                float* __restrict__ fT, unsigned short* __restrict__ xtc,
                                int C) {
    int idx = blockIdx.x;
    int ch = idx % C, b = idx / C;
    int s = threadIdx.x;
    if (s < 196) {
        float m = stats[2 * ch], r = stats[2 * ch + 1];
        float v = y[(size_t)idx * 196 + s];
        float o = fmaxf((v - m) * r * g[ch] + be[ch], 0.f);
        y[(size_t)idx * 196 + s] = o;
        if (fT) fT[((size_t)b * 196 + s) * C + ch] = o;
        if (xtc) {
            int G = C >> 6, gch = ch >> 6, cc = ch & 63;
            xtc[(((size_t)b * G + gch) * 208 + s) * 72 + cc] = f2bf(o);
        }
    }
}

// ---------------- catnum ----------------
__global__ void k_catnum(const float* __restrict__ inp, int A,
                         const float* __restrict__ w, const float* __restrict__ bias,
                         const float* __restrict__ g, const float* __restrict__ be,
                         float* __restrict__ outv) {
    int j = blockIdx.x;
    int lane = threadIdx.x;
    float v = 0.f;
    if (lane < 32) {
        v = bias[j];
        for (int k = 0; k < A; ++k) v += inp[lane * A + k] * w[j * A + k];
    }
    float s = (lane < 32) ? v : 0.f;
    float s2 = (lane < 32) ? v * v : 0.f;
    for (int m = 16; m; m >>= 1) { s += __shfl_xor(s, m, 32); s2 += __shfl_xor(s2, m, 32); }
    if (lane < 32) {
        float mean = s / 32.f;
        float var = s2 / 32.f - mean * mean;
        float rstd = rsqrtf(var + 1e-5f);
        float t = (v - mean) * rstd * g[j] + be[j];
        t = t / (1.f + expf(-t));
        outv[lane * 196 + j] = t;
    }
}

__global__ void k_textbuild(const float* __restrict__ toh, const float* __restrict__ tnm,
                            float* __restrict__ text, float* __restrict__ textT) {
    int idx = blockIdx.x;
    int b = idx / 45, c = idx - b * 45;
    int s = threadIdx.x;
    if (s < 196) {
        float v = (c < 30) ? toh[b * 196 + s] : tnm[b * 196 + s];
        text[(size_t)idx * 196 + s] = v;
        textT[((size_t)b * 196 + s) * 45 + c] = v;
    }
}

// ---------------- GCN dist (multi-row) ----------------
template <int C, int ROWS>
__global__ void k_gcn_dist_t(const float* __restrict__ f, const float* __restrict__ fT,
                             float* __restrict__ dist) {
    __shared__ float fi[ROWS][196];
    const int i0 = blockIdx.x * ROWS, b = blockIdx.y;
    const int tid = threadIdx.x;
    for (int idx = tid; idx < ROWS * 196; idx += 256) {
        int r = idx / 196, n = idx - r * 196;
        fi[r][n] = f[((size_t)(b * C + i0 + r)) * 196 + n];
    }
    __syncthreads();
    if (tid < C) {
        const float* ft = fT + (size_t)b * 196 * C + tid;
        float a[ROWS];
#pragma unroll
        for (int r = 0; r < ROWS; ++r) a[r] = 0.f;
#pragma unroll 4
        for (int n = 0; n < 196; ++n) {
            float v = ft[(size_t)n * C];
#pragma unroll
            for (int r = 0; r < ROWS; ++r) a[r] += fabsf(fi[r][n] - v);
        }
#pragma unroll
        for (int r = 0; r < ROWS; ++r)
            dist[((size_t)(b * C + i0 + r)) * C + tid] = expf(-a[r]);
    }
}

// ---------------- GCN spmm+fin (multi-row) ----------------
template <int C, int ROWS>
__global__ void k_gcn_spmmfin_t(const float* __restrict__ dist, const float* __restrict__ f,
                                const float* __restrict__ wt, const float* __restrict__ bias,
                                float* __restrict__ outp) {
    __shared__ float ds[ROWS][C];
    __shared__ float ts[ROWS][196];
    const int i0 = blockIdx.x * ROWS, b = blockIdx.y;
    const int tid = threadIdx.x;
    for (int idx = tid; idx < ROWS * C; idx += 256) {
        int r = idx / C, j = idx - r * C;
        ds[r][j] = dist[((size_t)(b * C + i0 + r)) * C + j];
    }
    __syncthreads();
    if (tid < 196) {
        float a[ROWS];
#pragma unroll
        for (int r = 0; r < ROWS; ++r) a[r] = 0.f;
#pragma unroll 4
        for (int j = 0; j < C; ++j) {
            float v = f[((size_t)b * C + j) * 196 + tid];
#pragma unroll
            for (int r = 0; r < ROWS; ++r) a[r] += ds[r][j] * v;
        }
#pragma unroll
        for (int r = 0; r < ROWS; ++r) ts[r][tid] = a[r];
    }
    __syncthreads();
    if (tid < 196) {
        float a[ROWS];
        float bi = bias[tid];
#pragma unroll
        for (int r = 0; r < ROWS; ++r) a[r] = bi;
#pragma unroll 4
        for (int n = 0; n < 196; ++n) {
            float wv = wt[(size_t)n * 196 + tid];
#pragma unroll
            for (int r = 0; r < ROWS; ++r) a[r] += ts[r][n] * wv;
        }
#pragma unroll
        for (int r = 0; r < ROWS; ++r) {
            size_t rr = ((size_t)(b * C + i0 + r)) * 196 + tid;
            outp[rr] = fmaxf(a[r], 0.f) + f[rr];
        }
    }
}

// ---------------- LN + relu(linear), multi-row, dual-layout q ----------------
template <int R, int ROWS>
__global__ void k_lnlin_t(const float* __restrict__ x, const float* __restrict__ g,
                          const float* __restrict__ be, const float* __restrict__ eT,
                          const float* __restrict__ eb, float* __restrict__ lnout,
                          float* __restrict__ qout, float* __restrict__ qT) {
    __shared__ float ls[ROWS][196];
    const int i0 = blockIdx.x * ROWS, b = blockIdx.y;
    const int tid = threadIdx.x;
    const int wv = tid >> 6, lane = tid & 63;
    for (int idx = tid; idx < ROWS * 196; idx += 256) {
        int r = idx / 196, n = idx - r * 196;
        ls[r][n] = x[((size_t)(b * R + i0 + r)) * 196 + n];
    }
    __syncthreads();
    for (int k = 0;; ++k) {
        int r = wv + 4 * k;
        if (r >= ROWS) break;
        float s = 0.f, s2 = 0.f;
        for (int j = lane; j < 196; j += 64) { float v = ls[r][j]; s += v; s2 += v * v; }
        for (int sh = 32; sh; sh >>= 1) { s += __shfl_xor(s, sh); s2 += __shfl_xor(s2, sh); }
        float mean = s / 196.f;
        float var = s2 / 196.f - mean * mean;
        float rstd = rsqrtf(var + 1e-6f);
        size_t rowo = ((size_t)(b * R + i0 + r)) * 196;
        for (int j = lane; j < 196; j += 64) {
            float l = (ls[r][j] - mean) * rstd * g[j] + be[j];
            ls[r][j] = l;
            lnout[rowo + j] = l;
        }
    }
    __syncthreads();
    if (tid < 196) {
        float a[ROWS];
        float bi = eb[tid];
#pragma unroll
        for (int r = 0; r < ROWS; ++r) a[r] = bi;
#pragma unroll 4
        for (int n = 0; n < 196; ++n) {
            float ev = eT[(size_t)n * 196 + tid];
#pragma unroll
            for (int r = 0; r < ROWS; ++r) a[r] += ls[r][n] * ev;
        }
#pragma unroll
        for (int r = 0; r < ROWS; ++r) {
            float q = fmaxf(a[r], 0.f);
            qout[((size_t)(b * R + i0 + r)) * 196 + tid] = q;
            qT[((size_t)b * 196 + tid) * R + i0 + r] = q;
        }
    }
}

// ---------------- fused cross-attention, multi-row, de-diverged ------------
template <int ROWS, int RA, int RB>
__global__ void k_attrow_t(const float* __restrict__ own, const float* __restrict__ ownT,
                           const float* __restrict__ oth, const float* __restrict__ othT,
                           const float* __restrict__ wAT, const float* __restrict__ bA,
                           const float* __restrict__ wBT, const float* __restrict__ bB,
                           const float* __restrict__ lnres, const float* __restrict__ res2,
                           float* __restrict__ feat, int cbase) {
    __shared__ float buf1[ROWS][196];      // qs -> fA
    __shared__ float sc[ROWS][176];        // scores -> probs (RA+RB=173)
    __shared__ float fB[ROWS][196];
    const int i0 = blockIdx.x * ROWS, b = blockIdx.y;
    const int tid = threadIdx.x;
    const int wv = tid >> 6, lane = tid & 63;
    const float* ownb = own + (size_t)b * RA * 196;
    const float* othb = oth + (size_t)b * RB * 196;
    for (int idx = tid; idx < ROWS * 196; idx += 256) {
        int r = idx / 196, n = idx - r * 196;
        buf1[r][n] = ownb[(size_t)(i0 + r) * 196 + n];
    }
    __syncthreads();
    {
        const bool act = tid < RA + RB;
        const float* ptr = nullptr;
        int stride = 1;
        if (act) {
            if (tid < RA) { ptr = ownT + (size_t)b * 196 * RA + tid; stride = RA; }
            else          { ptr = othT + (size_t)b * 196 * RB + (tid - RA); stride = RB; }
        }
        if (act) {
            float a[ROWS];
#pragma unroll
            for (int r = 0; r < ROWS; ++r) a[r] = 0.f;
#pragma unroll 4
            for (int n = 0; n < 196; ++n) {
                float kv = ptr[(size_t)n * stride];
#pragma unroll
                for (int r = 0; r < ROWS; ++r) a[r] += buf1[r][n] * kv;
            }
#pragma unroll
            for (int r = 0; r < ROWS; ++r) sc[r][tid] = a[r];
        }
    }
    __syncthreads();
    for (int k = 0;; ++k) {
        int r = wv + 4 * k;
        if (r >= ROWS) break;
        softseg(&sc[r][0], RA, lane);
        softseg(&sc[r][RA], RB, lane);
    }
    __syncthreads();
    if (tid < 196) {
        float a[ROWS];
#pragma unroll
        for (int r = 0; r < ROWS; ++r) a[r] = 0.f;
#pragma unroll 4
        for (int j = 0; j < RA; ++j) {
            float v = ownb[(size_t)j * 196 + tid];
#pragma unroll
            for (int r = 0; r < ROWS; ++r) a[r] += sc[r][j] * v;
        }
        float c[ROWS];
#pragma unroll
        for (int r = 0; r < ROWS; ++r) c[r] = 0.f;
#pragma unroll 4
        for (int j = 0; j < RB; ++j) {
            float v = othb[(size_t)j * 196 + tid];
#pragma unroll
            for (int r = 0; r < ROWS; ++r) c[r] += sc[r][RA + j] * v;
        }
#pragma unroll
        for (int r = 0; r < ROWS; ++r) { buf1[r][tid] = a[r]; fB[r][tid] = c[r]; }
    }
    __syncthreads();
    if (tid < 196) {
        float a[ROWS];
        float bb = bA[tid] + bB[tid];
#pragma unroll
        for (int r = 0; r < ROWS; ++r) {
            size_t rr = ((size_t)(b * RA + i0 + r)) * 196 + tid;
            a[r] = bb + lnres[rr] + res2[rr];
        }
#pragma unroll 4
        for (int n = 0; n < 196; ++n) {
            float wa = wAT[(size_t)n * 196 + tid];
            float wb = wBT[(size_t)n * 196 + tid];
#pragma unroll
            for (int r = 0; r < ROWS; ++r) a[r] += buf1[r][n] * wa + fB[r][n] * wb;
        }
#pragma unroll
        for (int r = 0; r < ROWS; ++r)
            feat[((size_t)(b * 173 + cbase + i0 + r)) * 196 + tid] = a[r];
    }
}

// ---------------- 1x1 conv, multi-row; RES=0 writes qT, RES=1 res+rowsum ----
template <int RES, int ROWS>
__global__ void k_conv1x1_t(const float* __restrict__ x, const float* __restrict__ w,
                            const float* __restrict__ bias, const float* __restrict__ res,
                            float* __restrict__ outp, float* __restrict__ aux) {
    __shared__ float wsm[ROWS][173];
    __shared__ float vals[ROWS][200];
    const int o0 = blockIdx.x * ROWS, b = blockIdx.y;
    const int tid = threadIdx.x;
    const int nv = (173 - o0 < ROWS) ? (173 - o0) : ROWS;
    for (int idx = tid; idx < nv * 173; idx += 256) {
        int r = idx / 173, c = idx - r * 173;
        wsm[r][c] = w[(size_t)(o0 + r) * 173 + c];
    }
    __syncthreads();
    if (tid < 196) {
        float a[ROWS];
#pragma unroll
        for (int r = 0; r < ROWS; ++r) a[r] = (r < nv) ? bias[o0 + r] : 0.f;
#pragma unroll 4
        for (int c = 0; c < 173; ++c) {
            float xv = x[((size_t)(b * 173 + c)) * 196 + tid];
#pragma unroll
            for (int r = 0; r < ROWS; ++r) a[r] += wsm[r][c] * xv;
        }
#pragma unroll
        for (int r = 0; r < ROWS; ++r) {
            if (r < nv) {
                float v = fmaxf(a[r], 0.f);
                size_t rr = ((size_t)(b * 173 + o0 + r)) * 196 + tid;
                if (RES) v += res[rr];
                outp[rr] = v;
                if (!RES) aux[((size_t)b * 196 + tid) * 173 + o0 + r] = v;
                if (RES) vals[r][tid] = v;
            }
        }
    }
    if (RES) {
        __syncthreads();
        int wv = tid >> 6, lane = tid & 63;
        for (int k = 0;; ++k) {
            int r = wv + 4 * k;
            if (r >= nv) break;
            float s = 0.f;
            for (int j = lane; j < 196; j += 64) s += vals[r][j];
            for (int sh = 32; sh; sh >>= 1) s += __shfl_xor(s, sh);
            if (lane == 0) aux[(size_t)b * 173 + o0 + r] = s;
        }
    }
}

// ---------------- CMSA attention (multi-row, writes A^T) ----------------
template <int ROWS>
__global__ void k_cmsa_att_t(const float* __restrict__ q, const float* __restrict__ qT,
                             float* __restrict__ AT) {
    __shared__ float colt[ROWS][176];
    __shared__ float sc[ROWS][200];
    const int i0 = blockIdx.x * ROWS, b = blockIdx.y;
    const int tid = threadIdx.x;
    for (int idx = tid; idx < ROWS * 173; idx += 256) {
        int r = idx / 173, c = idx - r * 173;
        colt[r][c] = qT[((size_t)b * 196 + i0 + r) * 173 + c];
    }
    __syncthreads();
    if (tid < 196) {
        float a[ROWS];
#pragma unroll
        for (int r = 0; r < ROWS; ++r) a[r] = 0.f;
#pragma unroll 4
        for (int c = 0; c < 173; ++c) {
            float qv = q[((size_t)(b * 173 + c)) * 196 + tid];
#pragma unroll
            for (int r = 0; r < ROWS; ++r) a[r] += colt[r][c] * qv;
        }
#pragma unroll
        for (int r = 0; r < ROWS; ++r) sc[r][tid] = a[r];
    }
    __syncthreads();
    int wv = tid >> 6, lane = tid & 63;
    for (int k = 0;; ++k) {
        int r = wv + 4 * k;
        if (r >= ROWS) break;
        softseg(&sc[r][0], 196, lane);
    }
    __syncthreads();
    for (int idx = tid; idx < ROWS * 196; idx += 256) {
        int r = idx / 196, j = idx - r * 196;
        AT[((size_t)b * 196 + j) * 196 + i0 + r] = sc[r][j];
    }
}

// ---------------- CMSA apply (multi-row) ----------------
template <int ROWS>
__global__ void k_cmsa_apply_t(const float* __restrict__ AT, const float* __restrict__ q,
                               float* __restrict__ fea) {
    __shared__ float qsr[ROWS][196];
    const int c0 = blockIdx.x * ROWS, b = blockIdx.y;
    const int tid = threadIdx.x;
    const int nv = (173 - c0 < ROWS) ? (173 - c0) : ROWS;
    for (int idx = tid; idx < nv * 196; idx += 256) {
        int r = idx / 196, n = idx - r * 196;
        qsr[r][n] = q[((size_t)(b * 173 + c0 + r)) * 196 + n];
    }
    __syncthreads();
    if (tid < 196) {
        float a[ROWS];
#pragma unroll
        for (int r = 0; r < ROWS; ++r) a[r] = 0.f;
        const float* at = AT + (size_t)b * 196 * 196 + tid;
#pragma unroll 4
        for (int j = 0; j < 196; ++j) {
            float av = at[(size_t)j * 196];
#pragma unroll
            for (int r = 0; r < ROWS; ++r) a[r] += av * qsr[r][j];
        }
#pragma unroll
        for (int r = 0; r < ROWS; ++r)
            if (r < nv) fea[((size_t)(b * 173 + c0 + r)) * 196 + tid] = a[r];
    }
}

// ---------------- final classifier ----------------
__global__ void k_finale(const float* __restrict__ toh, const float* __restrict__ tnm,
                         const float* __restrict__ rowsum, const float* __restrict__ cls_w,
                         const float* __restrict__ cls_b, float* __restrict__ out) {
    int b = blockIdx.x;
    __shared__ float r1[4], r2[4];
    int tid = threadIdx.x;
    float a = (tid < 196) ? toh[b * 196 + tid] : 0.f;
    float c = (tid < 196) ? tnm[b * 196 + tid] : 0.f;
    for (int sh = 32; sh; sh >>= 1) { a += __shfl_xor(a, sh); c += __shfl_xor(c, sh); }
    if ((tid & 63) == 0) { r1[tid >> 6] = a; r2[tid >> 6] = c; }
    __syncthreads();
    if (tid < 2) {
        float soh = r1[0] + r1[1] + r1[2] + r1[3];
        float snm = r2[0] + r2[1] + r2[2] + r2[3];
        const float* wrow = &cls_w[tid * 218];
        float acc = cls_b[tid];
        float w1 = 0.f, w2 = 0.f;
        for (int k = 0; k < 30; ++k) w1 += wrow[k];
        for (int k = 30; k < 45; ++k) w2 += wrow[k];
        acc += soh * w1 + snm * w2;
        for (int k = 0; k < 173; ++k) acc += wrow[45 + k] * rowsum[(size_t)b * 173 + k];
        out[b * 2 + tid] = acc;
    }
}

// ---------------------------------------------------------------------------
extern "C" void kernel_launch(void* const* d_in, const int* in_sizes, int n_in,
                              void* d_out, int out_size, void* d_ws, size_t ws_size,
                              hipStream_t stream) {
    const float* x      = (const float*)d_in[0];
    const float* oneHot = (const float*)d_in[1];
    const float* num    = (const float*)d_in[2];
    const float* c1_w1  = (const float*)d_in[3];
    const float* c1_g1  = (const float*)d_in[5];
    const float* c1_be1 = (const float*)d_in[6];
    const float* c1_w2  = (const float*)d_in[7];
    const float* c1_g2  = (const float*)d_in[9];
    const float* c1_be2 = (const float*)d_in[10];
    const float* oh_w   = (const float*)d_in[11];
    const float* oh_b   = (const float*)d_in[12];
    const float* oh_g   = (const float*)d_in[13];
    const float* oh_be  = (const float*)d_in[14];
    const float* nm_w   = (const float*)d_in[15];
    const float* nm_b   = (const float*)d_in[16];
    const float* nm_g   = (const float*)d_in[17];
    const float* nm_be  = (const float*)d_in[18];
    const float* gm1_w  = (const float*)d_in[19];
    const float* gm1_b  = (const float*)d_in[20];
    const float* gm2_w  = (const float*)d_in[21];
    const float* gm2_b  = (const float*)d_in[22];
    const float* ln1_g  = (const float*)d_in[23];
    const float* ln1_b  = (const float*)d_in[24];
    const float* ln2_g  = (const float*)d_in[25];
    const float* ln2_b  = (const float*)d_in[26];
    const float* e1_w   = (const float*)d_in[27];
    const float* e1_b   = (const float*)d_in[28];
    const float* e2_w   = (const float*)d_in[29];
    const float* e2_b   = (const float*)d_in[30];
    const float* f1_w   = (const float*)d_in[31];
    const float* f1_b   = (const float*)d_in[32];
    const float* f2_w   = (const float*)d_in[33];
    const float* f2_b   = (const float*)d_in[34];
    const float* f3_w   = (const float*)d_in[35];
    const float* f3_b   = (const float*)d_in[36];
    const float* f4_w   = (const float*)d_in[37];
    const float* f4_b   = (const float*)d_in[38];
    const float* cm_w   = (const float*)d_in[39];
    const float* cm_b   = (const float*)d_in[40];
    const float* cmf_w  = (const float*)d_in[41];
    const float* cmf_b  = (const float*)d_in[42];
    const float* cls_w  = (const float*)d_in[43];
    const float* cls_b  = (const float*)d_in[44];
    float* out = (float*)d_out;
    float* W = (float*)d_ws;

    const size_t L = 802816;
    const size_t T = 282240;
    const size_t F3 = 1085056;
    const size_t o_A    = 0;
    const size_t o_B    = L;
    const size_t o_C    = 2 * L;
    const size_t o_part = 3 * L;          // conv partials [3L, 8L) (G<=5)
    const size_t o_iq   = 3 * L;
    const size_t o_tq   = 4 * L;
    const size_t o_t1   = 4 * L + T;
    const size_t o_t3   = 4 * L + 2 * T;
    const size_t o_ln2  = 4 * L + 3 * T;
    const size_t o_toh  = 4 * L + 4 * T;
    const size_t o_tnm  = o_toh + 6272;
    const size_t o_st   = o_tnm + 6272;
    const size_t o_wT   = o_st + 1024;
    const size_t o_feat = o_wT + 8 * 38416;
    const size_t o_q    = o_feat + F3;
    const size_t o_fea  = o_q + F3;
    const size_t o_Acm  = o_fea + F3;     // A^T [32,196,196]; gcn dists earlier
    const size_t o_d1   = o_Acm;
    const size_t o_d2   = o_Acm + 524288;
    // conv-phase-only buffers (chunk-major bf16):
    const size_t o_xt1 = 9 * L;                       // 32*5*208*72/2 = 1,198,080 floats
    const size_t o_xt2 = o_xt1 + 1198080;             // 32*2*208*72/2 =   479,232
    const size_t o_wp1 = o_xt2 + 479232;              // 27*128*320/2  =   552,960
    const size_t o_wp2 = o_wp1 + 552960;              // 27*128*128/2  =   221,184
    const size_t o_tr  = o_wp2 + 221184;              // = 9,676,800
    const size_t o_rs  = o_tr + F3;                   // rowsum 32*173

    float* part = W + o_part;
    unsigned short* xt1 = (unsigned short*)(W + o_xt1);
    unsigned short* xt2 = (unsigned short*)(W + o_xt2);
    unsigned short* wp1 = (unsigned short*)(W + o_wp1);
    unsigned short* wp2 = (unsigned short*)(W + o_wp2);
    float* gm1T = W + o_wT + 0 * 38416;
    float* gm2T = W + o_wT + 1 * 38416;
    float* e1T  = W + o_wT + 2 * 38416;
    float* e2T  = W + o_wT + 3 * 38416;
    float* f1T  = W + o_wT + 4 * 38416;
    float* f2T  = W + o_wT + 5 * 38416;
    float* f3T  = W + o_wT + 6 * 38416;
    float* f4T  = W + o_wT + 7 * 38416;

    // ---- conv prep ----
    k_wpack<<<(27 * 128 * 40 + 255) / 256, 256, 0, stream>>>(c1_w1, wp1, 320);
    k_wpack<<<(27 * 128 * 16 + 255) / 256, 256, 0, stream>>>(c1_w2, wp2, 128);
    k_xt_c<<<dim3((5 * 208 * 36 + 255) / 256, 32), 256, 0, stream>>>(x, xt1, 320, 5);

    // ---- conv1: 5 chunks x 2 nh(NT=4) x 2 mh -> 640 blocks; BN also emits
    //      conv2's chunk-major bf16 input (xt2) ----
    k_convchunk3<320, 5, 4, 2><<<dim3(20, 32), 256, 0, stream>>>(xt1, wp1, part);
    k_reduceG<5><<<3136, 256, 0, stream>>>(part, W + o_A, 802816);
    k_bn_stats<<<128, 256, 0, stream>>>(W + o_A, W + o_st, 128);
    k_bn_apply_relu<<<4096, 256, 0, stream>>>(W + o_A, W + o_st, c1_g1, c1_be1,
                                              nullptr, xt2, 128);

    // ---- conv2: 2 chunks x 4 nh(NT=2) x 2 mh -> 512 blocks ----
    k_convchunk3<128, 2, 2, 4><<<dim3(16, 32), 256, 0, stream>>>(xt2, wp2, part);
    k_reduceG<2><<<3136, 256, 0, stream>>>(part, W + o_B, 802816);
    k_bn_stats<<<128, 256, 0, stream>>>(W + o_B, W + o_st + 512, 128);
    k_bn_apply_relu<<<4096, 256, 0, stream>>>(W + o_B, W + o_st + 512, c1_g2, c1_be2,
                                              W + o_tr, nullptr, 128);

    // ---- weight transposes ----
    P8 p8;
    p8.p[0] = gm1_w; p8.p[1] = gm2_w; p8.p[2] = e1_w; p8.p[3] = e2_w;
    p8.p[4] = f1_w;  p8.p[5] = f2_w;  p8.p[6] = f3_w; p8.p[7] = f4_w;
    k_transpose8<<<dim3(196, 8), 256, 0, stream>>>(p8, W + o_wT);

    // ---- catnum / text ----
    k_catnum<<<196, 64, 0, stream>>>(oneHot, 24, oh_w, oh_b, oh_g, oh_be, W + o_toh);
    k_catnum<<<196, 64, 0, stream>>>(num, 11, nm_w, nm_b, nm_g, nm_be, W + o_tnm);
    k_textbuild<<<32 * 45, 256, 0, stream>>>(W + o_toh, W + o_tnm, W + o_t1, W + o_tr + L);

    // ---- GCN img ----
    k_gcn_dist_t<128, 4><<<dim3(32, 32), 256, 0, stream>>>(W + o_B, W + o_tr, W + o_d1);
    k_gcn_spmmfin_t<128, 4><<<dim3(32, 32), 256, 0, stream>>>(W + o_d1, W + o_B, gm1T,
                                                              gm1_b, W + o_C);
    // ---- GCN text ----
    k_gcn_dist_t<45, 3><<<dim3(15, 32), 256, 0, stream>>>(W + o_t1, W + o_tr + L, W + o_d2);
    k_gcn_spmmfin_t<45, 3><<<dim3(15, 32), 256, 0, stream>>>(W + o_d2, W + o_t1, gm2T,
                                                             gm2_b, W + o_t3);

    // ---- LN + q projections ----
    k_lnlin_t<128, 4><<<dim3(32, 32), 256, 0, stream>>>(W + o_C, ln1_g, ln1_b, e1T, e1_b,
                                                        W + o_B, W + o_iq, W + o_tr);
    k_lnlin_t<45, 3><<<dim3(15, 32), 256, 0, stream>>>(W + o_t3, ln2_g, ln2_b, e2T, e2_b,
                                                       W + o_ln2, W + o_tq, W + o_tr + L);

    // ---- cross-attention -> feat ----
    k_attrow_t<4, 128, 45><<<dim3(32, 32), 256, 0, stream>>>(
        W + o_iq, W + o_tr, W + o_tq, W + o_tr + L,
        f1T, f1_b, f3T, f3_b, W + o_B, W + o_C, W + o_feat, 0);
    k_attrow_t<3, 45, 128><<<dim3(15, 32), 256, 0, stream>>>(
        W + o_tq, W + o_tr + L, W + o_iq, W + o_tr,
        f2T, f2_b, f4T, f4_b, W + o_ln2, W + o_t3, W + o_feat, 128);

    // ---- CMSA ----
    k_conv1x1_t<0, 4><<<dim3(44, 32), 256, 0, stream>>>(W + o_feat, cm_w, cm_b, nullptr,
                                                        W + o_q, W + o_tr);
    k_cmsa_att_t<4><<<dim3(49, 32), 256, 0, stream>>>(W + o_q, W + o_tr, W + o_Acm);
    k_cmsa_apply_t<4><<<dim3(44, 32), 256, 0, stream>>>(W + o_Acm, W + o_q, W + o_fea);
    k_conv1x1_t<1, 4><<<dim3(44, 32), 256, 0, stream>>>(W + o_fea, cmf_w, cmf_b, W + o_feat,
                                                        W + o_q, W + o_rs);

    // ---- final classifier ----
    k_finale<<<32, 256, 0, stream>>>(W + o_toh, W + o_tnm, W + o_rs, cls_w, cls_b, out);
}

// Round 12
// 502.187 us; speedup vs baseline: 1.1219x; 1.1219x over previous
//
#include <hip/hip_runtime.h>
#include <hip/hip_bf16.h>

// ---------------------------------------------------------------------------
// mv3Dunet_down_text_cmsa forward. Round 12: conv inner loop reads B from a
// double-buffered LDS tile staged asynchronously per tap via
// __builtin_amdgcn_global_load_lds (pre-swizzled source, swizzled ds_read).
// r11 diagnosis: compiler allocated 1 B-register set (VGPR=52) -> per-tap
// vmcnt(0)-serialized HBM loads (wp evicted from L2 by xs streaming).
// Tail identical to round 11.
// ---------------------------------------------------------------------------

using bf16x8 = __attribute__((ext_vector_type(8))) short;
using f32x4  = __attribute__((ext_vector_type(4))) float;

typedef const __attribute__((address_space(1))) void gas_void;
typedef __attribute__((address_space(3))) void las_void;

__device__ __forceinline__ unsigned short f2bf(float f) {
    unsigned int u = __float_as_uint(f);
    u += 0x7FFFu + ((u >> 16) & 1u);
    return (unsigned short)(u >> 16);
}

// in-place softmax over s[0..len) using one wave's 64 lanes
__device__ __forceinline__ void softseg(float* s, int len, int lane) {
    float m = -3.4e38f;
    for (int j = lane; j < len; j += 64) m = fmaxf(m, s[j]);
    for (int sh = 32; sh; sh >>= 1) m = fmaxf(m, __shfl_xor(m, sh));
    float sum = 0.f;
    for (int j = lane; j < len; j += 64) { float e = expf(s[j] - m); s[j] = e; sum += e; }
    for (int sh = 32; sh; sh >>= 1) sum += __shfl_xor(sum, sh);
    float inv = 1.f / sum;
    for (int j = lane; j < len; j += 64) s[j] *= inv;
}

// ---------------- X -> chunk-major bf16: xt[b][g][208][72] ----------------
__global__ void k_xt_c(const float* __restrict__ x, unsigned short* __restrict__ xt,
                       int IC, int G) {
    int b = blockIdx.y;
    int tot = G * 208 * 36;                  // uint writes
    int idx = blockIdx.x * 256 + threadIdx.x;
    if (idx >= tot) return;
    int g = idx / (208 * 36); int r = idx - g * 208 * 36;
    int s = r / 36, cp = r - s * 36;
    int cc = cp * 2;
    int ic = g * 64 + cc;
    unsigned int lo = 0, hi = 0;
    if (s < 196 && cc < 64 && ic < IC)         lo = f2bf(x[((size_t)b * IC + ic) * 196 + s]);
    if (s < 196 && cc + 1 < 64 && ic + 1 < IC) hi = f2bf(x[((size_t)b * IC + ic + 1) * 196 + s]);
    ((unsigned int*)xt)[(size_t)b * tot + idx] = lo | (hi << 16);
}

// ---------------- weight pack: w[oc][ic][27] f32 -> wp[t][oc][ic] bf16 ------
__global__ void k_wpack(const float* __restrict__ w, unsigned short* __restrict__ wp,
                        int IC) {
    int nc = IC >> 3;
    int idx = blockIdx.x * 256 + threadIdx.x;
    if (idx >= 27 * 128 * nc) return;
    int c = idx % nc; int r = idx / nc; int oc = r & 127; int t = r >> 7;
    const float* ws = w + ((size_t)oc * IC + c * 8) * 27 + t;
    unsigned int o0 = f2bf(ws[0])   | ((unsigned int)f2bf(ws[27])  << 16);
    unsigned int o1 = f2bf(ws[54])  | ((unsigned int)f2bf(ws[81])  << 16);
    unsigned int o2 = f2bf(ws[108]) | ((unsigned int)f2bf(ws[135]) << 16);
    unsigned int o3 = f2bf(ws[162]) | ((unsigned int)f2bf(ws[189]) << 16);
    uint4 v; v.x = o0; v.y = o1; v.z = o2; v.w = o3;
    ((uint4*)wp)[idx] = v;
}

// ---------------- MFMA conv: LDS-double-buffered B, async staged ------------
// Block = (g ic-chunk, nh N-slice of NT*16 oc, mh m-half, b).
// xs = A chunk [208][72] bf16; bbuf = 2 x (NT*16 rows x 128B) B tile,
// staged via global_load_lds with source col ^ ((row&7)<<4) swizzle.
template <int IC, int G, int NT, int NH>
__global__ __launch_bounds__(256, 3) void k_convchunk4(
    const unsigned short* __restrict__ xt, const unsigned short* __restrict__ wp,
    float* __restrict__ part) {
    __shared__ unsigned short xs[208 * 72];
    __shared__ char bbuf[2][NT * 2048];
    const int tid = threadIdx.x;
    const int bx = blockIdx.x, b = blockIdx.y;
    const int mh = bx & 1;
    const int nh = (bx >> 1) % NH;
    const int g  = (bx >> 1) / NH;
    const int w = tid >> 6, l = tid & 63;

    // stage A chunk (plain copy, once)
    {
        const bf16x8* s8 = (const bf16x8*)(xt + ((size_t)b * G + g) * (208 * 72));
        bf16x8* d8 = (bf16x8*)xs;
        for (int c = tid; c < 208 * 72 / 8; c += 256) d8[c] = s8[c];
    }

    const char* wslice = (const char*)wp +
                         ((size_t)(nh * NT * 16) * IC + (size_t)g * 64) * 2;
    // async-stage tap t's B tile into bbuf[t&1]; wave w covers NT*512 bytes
    auto stageB = [&](int t) {
        char* dst = &bbuf[t & 1][w * (NT * 512)];
        const char* wt_ = wslice + (size_t)t * 128 * IC * 2;
#pragma unroll
        for (int c = 0; c < NT / 2; ++c) {
            int q = w * (NT * 512) + c * 1024 + l * 16;   // byte offset in tile
            int row = q >> 7, col = q & 127;
            int scol = col ^ ((row & 7) << 4);            // inverse swizzle
            gas_void* src = (gas_void*)(wt_ + (size_t)row * IC * 2 + scol);
            __builtin_amdgcn_global_load_lds(src, (las_void*)(dst + c * 1024),
                                             16, 0, 0);
        }
    };

    const int lane = tid & 63;
    const int a = lane & 15, kg = lane >> 4;

    int md[2], mhh[2], mw[2];
#pragma unroll
    for (int i = 0; i < 2; ++i) {
        int m = (mh * 8 + (tid >> 6) * 2 + i) * 16 + a;
        md[i] = m / 49; int rr = m - md[i] * 49;
        mhh[i] = rr / 7; mw[i] = rr - mhh[i] * 7;
    }

    f32x4 acc[2][NT];
#pragma unroll
    for (int i = 0; i < 2; ++i)
#pragma unroll
        for (int nt = 0; nt < NT; ++nt) acc[i][nt] = (f32x4){0.f, 0.f, 0.f, 0.f};

    const bf16x8 zv = {0, 0, 0, 0, 0, 0, 0, 0};

    stageB(0);
    __syncthreads();          // xs writes + B0 staging drained

    for (int t = 0; t < 27; ++t) {
        if (t < 26) stageB(t + 1);
        const int kd = t / 9, kh = (t / 3) % 3, kw = t % 3;
        int rsrc[2]; bool ok[2];
#pragma unroll
        for (int i = 0; i < 2; ++i) {
            int d2 = md[i] + kd - 1, h2 = mhh[i] + kh - 1, w2 = mw[i] + kw - 1;
            ok[i] = ((unsigned)d2 < 4u) & ((unsigned)h2 < 7u) & ((unsigned)w2 < 7u);
            rsrc[i] = ok[i] ? (d2 * 49 + h2 * 7 + w2) : 0;
        }
        bf16x8 A[2][2];
#pragma unroll
        for (int kk = 0; kk < 2; ++kk)
#pragma unroll
            for (int i = 0; i < 2; ++i) {
                bf16x8 v = *(const bf16x8*)(xs + rsrc[i] * 72 + kk * 32 + kg * 8);
                A[kk][i] = ok[i] ? v : zv;
            }
        const char* bb = &bbuf[t & 1][0];
#pragma unroll
        for (int kk = 0; kk < 2; ++kk)
#pragma unroll
            for (int nt = 0; nt < NT; ++nt) {
                int row = nt * 16 + a;
                int cb = (kk * 64 + kg * 16) ^ ((row & 7) << 4);
                bf16x8 B = *(const bf16x8*)(bb + row * 128 + cb);
#pragma unroll
                for (int i = 0; i < 2; ++i)
                    acc[i][nt] = __builtin_amdgcn_mfma_f32_16x16x32_bf16(
                        A[kk][i], B, acc[i][nt], 0, 0, 0);
            }
        __syncthreads();      // next-tap staging drained; buf[t&1] free to reuse
    }

    float* dst = part + ((size_t)g * 32 + b) * (128 * 196);
#pragma unroll
    for (int i = 0; i < 2; ++i) {
        int m0 = (mh * 8 + (tid >> 6) * 2 + i) * 16 + kg * 4;
        if (m0 < 196) {
#pragma unroll
            for (int nt = 0; nt < NT; ++nt) {
                int oc = nh * NT * 16 + nt * 16 + a;
                *(f32x4*)(dst + (size_t)oc * 196 + m0) = acc[i][nt];
            }
        }
    }
}

// sum G partials
template <int G>
__global__ void k_reduceG(const float* __restrict__ part, float* __restrict__ y, int n) {
    int i = blockIdx.x * blockDim.x + threadIdx.x;
    if (i < n) {
        float s = 0.f;
#pragma unroll
        for (int g = 0; g < G; ++g) s += part[(size_t)g * n + i];
        y[i] = s;
    }
}

// ---------------- transpose of 8 [196,196] matrices ----------------
struct P8 { const float* p[8]; };
__global__ void k_transpose8(P8 ws_in, float* __restrict__ wt) {
    int i = blockIdx.x, m = blockIdx.y;
    const float* w = ws_in.p[m];
    float* o = wt + (size_t)m * 38416;
    for (int t = threadIdx.x; t < 196; t += blockDim.x)
        o[(size_t)i * 196 + t] = w[(size_t)t * 196 + i];
}

// ---------------- BN ----------------
__global__ void k_bn_stats(const float* __restrict__ y, float* __restrict__ stats,
                           int C) {
    int ch = blockIdx.x; int tid = threadIdx.x;
    float s = 0.f, s2 = 0.f;
    for (int b = 0; b < 32; ++b) {
        const float* p = &y[(size_t)(b * C + ch) * 196];
        for (int i = tid; i < 196; i += 256) { float v = p[i]; s += v; s2 += v * v; }
    }
    __shared__ float r1[4], r2[4];
    for (int sh = 32; sh; sh >>= 1) { s += __shfl_xor(s, sh); s2 += __shfl_xor(s2, sh); }
    if ((tid & 63) == 0) { r1[tid >> 6] = s; r2[tid >> 6] = s2; }
    __syncthreads();
    if (tid == 0) {
        float S = r1[0] + r1[1] + r1[2] + r1[3];
        float S2 = r2[0] + r2[1] + r2[2] + r2[3];
        float m = S / 6272.f;
        float v = S2 / 6272.f - m * m;
        stats[2 * ch] = m;
        stats[2 * ch + 1] = rsqrtf(v + 1e-5f);
    }
}

// optional fT (transposed twin) and xtc (chunk-major bf16 for next conv)
__global__ void k_bn_apply_relu(float* __restrict__ y, const float* __restrict__ stats,
                                const float* __restrict__ g, const float* __restrict__ be,
                                float* __restrict__ fT, unsigned short* __restrict__ xtc,
                                int C) {
    int idx = blockIdx.x;
    int ch = idx % C, b = idx / C;
    int s = threadIdx.x;
    if (s < 196) {
        float m = stats[2 * ch], r = stats[2 * ch + 1];
        float v = y[(size_t)idx * 196 + s];
        float o = fmaxf((v - m) * r * g[ch] + be[ch], 0.f);
        y[(size_t)idx * 196 + s] = o;
        if (fT) fT[((size_t)b * 196 + s) * C + ch] = o;
        if (xtc) {
            int G = C >> 6, gch = ch >> 6, cc = ch & 63;
            xtc[(((size_t)b * G + gch) * 208 + s) * 72 + cc] = f2bf(o);
        }
    }
}

// ---------------- catnum ----------------
__global__ void k_catnum(const float* __restrict__ inp, int A,
                         const float* __restrict__ w, const float* __restrict__ bias,
                         const float* __restrict__ g, const float* __restrict__ be,
                         float* __restrict__ outv) {
    int j = blockIdx.x;
    int lane = threadIdx.x;
    float v = 0.f;
    if (lane < 32) {
        v = bias[j];
        for (int k = 0; k < A; ++k) v += inp[lane * A + k] * w[j * A + k];
    }
    float s = (lane < 32) ? v : 0.f;
    float s2 = (lane < 32) ? v * v : 0.f;
    for (int m = 16; m; m >>= 1) { s += __shfl_xor(s, m, 32); s2 += __shfl_xor(s2, m, 32); }
    if (lane < 32) {
        float mean = s / 32.f;
        float var = s2 / 32.f - mean * mean;
        float rstd = rsqrtf(var + 1e-5f);
        float t = (v - mean) * rstd * g[j] + be[j];
        t = t / (1.f + expf(-t));
        outv[lane * 196 + j] = t;
    }
}

__global__ void k_textbuild(const float* __restrict__ toh, const float* __restrict__ tnm,
                            float* __restrict__ text, float* __restrict__ textT) {
    int idx = blockIdx.x;
    int b = idx / 45, c = idx - b * 45;
    int s = threadIdx.x;
    if (s < 196) {
        float v = (c < 30) ? toh[b * 196 + s] : tnm[b * 196 + s];
        text[(size_t)idx * 196 + s] = v;
        textT[((size_t)b * 196 + s) * 45 + c] = v;
    }
}

// ---------------- GCN dist (multi-row) ----------------
template <int C, int ROWS>
__global__ void k_gcn_dist_t(const float* __restrict__ f, const float* __restrict__ fT,
                             float* __restrict__ dist) {
    __shared__ float fi[ROWS][196];
    const int i0 = blockIdx.x * ROWS, b = blockIdx.y;
    const int tid = threadIdx.x;
    for (int idx = tid; idx < ROWS * 196; idx += 256) {
        int r = idx / 196, n = idx - r * 196;
        fi[r][n] = f[((size_t)(b * C + i0 + r)) * 196 + n];
    }
    __syncthreads();
    if (tid < C) {
        const float* ft = fT + (size_t)b * 196 * C + tid;
        float a[ROWS];
#pragma unroll
        for (int r = 0; r < ROWS; ++r) a[r] = 0.f;
#pragma unroll 4
        for (int n = 0; n < 196; ++n) {
            float v = ft[(size_t)n * C];
#pragma unroll
            for (int r = 0; r < ROWS; ++r) a[r] += fabsf(fi[r][n] - v);
        }
#pragma unroll
        for (int r = 0; r < ROWS; ++r)
            dist[((size_t)(b * C + i0 + r)) * C + tid] = expf(-a[r]);
    }
}

// ---------------- GCN spmm+fin (multi-row) ----------------
template <int C, int ROWS>
__global__ void k_gcn_spmmfin_t(const float* __restrict__ dist, const float* __restrict__ f,
                                const float* __restrict__ wt, const float* __restrict__ bias,
                                float* __restrict__ outp) {
    __shared__ float ds[ROWS][C];
    __shared__ float ts[ROWS][196];
    const int i0 = blockIdx.x * ROWS, b = blockIdx.y;
    const int tid = threadIdx.x;
    for (int idx = tid; idx < ROWS * C; idx += 256) {
        int r = idx / C, j = idx - r * C;
        ds[r][j] = dist[((size_t)(b * C + i0 + r)) * C + j];
    }
    __syncthreads();
    if (tid < 196) {
        float a[ROWS];
#pragma unroll
        for (int r = 0; r < ROWS; ++r) a[r] = 0.f;
#pragma unroll 4
        for (int j = 0; j < C; ++j) {
            float v = f[((size_t)b * C + j) * 196 + tid];
#pragma unroll
            for (int r = 0; r < ROWS; ++r) a[r] += ds[r][j] * v;
        }
#pragma unroll
        for (int r = 0; r < ROWS; ++r) ts[r][tid] = a[r];
    }
    __syncthreads();
    if (tid < 196) {
        float a[ROWS];
        float bi = bias[tid];
#pragma unroll
        for (int r = 0; r < ROWS; ++r) a[r] = bi;
#pragma unroll 4
        for (int n = 0; n < 196; ++n) {
            float wv = wt[(size_t)n * 196 + tid];
#pragma unroll
            for (int r = 0; r < ROWS; ++r) a[r] += ts[r][n] * wv;
        }
#pragma unroll
        for (int r = 0; r < ROWS; ++r) {
            size_t rr = ((size_t)(b * C + i0 + r)) * 196 + tid;
            outp[rr] = fmaxf(a[r], 0.f) + f[rr];
        }
    }
}

// ---------------- LN + relu(linear), multi-row, dual-layout q ----------------
template <int R, int ROWS>
__global__ void k_lnlin_t(const float* __restrict__ x, const float* __restrict__ g,
                          const float* __restrict__ be, const float* __restrict__ eT,
                          const float* __restrict__ eb, float* __restrict__ lnout,
                          float* __restrict__ qout, float* __restrict__ qT) {
    __shared__ float ls[ROWS][196];
    const int i0 = blockIdx.x * ROWS, b = blockIdx.y;
    const int tid = threadIdx.x;
    const int wv = tid >> 6, lane = tid & 63;
    for (int idx = tid; idx < ROWS * 196; idx += 256) {
        int r = idx / 196, n = idx - r * 196;
        ls[r][n] = x[((size_t)(b * R + i0 + r)) * 196 + n];
    }
    __syncthreads();
    for (int k = 0;; ++k) {
        int r = wv + 4 * k;
        if (r >= ROWS) break;
        float s = 0.f, s2 = 0.f;
        for (int j = lane; j < 196; j += 64) { float v = ls[r][j]; s += v; s2 += v * v; }
        for (int sh = 32; sh; sh >>= 1) { s += __shfl_xor(s, sh); s2 += __shfl_xor(s2, sh); }
        float mean = s / 196.f;
        float var = s2 / 196.f - mean * mean;
        float rstd = rsqrtf(var + 1e-6f);
        size_t rowo = ((size_t)(b * R + i0 + r)) * 196;
        for (int j = lane; j < 196; j += 64) {
            float l = (ls[r][j] - mean) * rstd * g[j] + be[j];
            ls[r][j] = l;
            lnout[rowo + j] = l;
        }
    }
    __syncthreads();
    if (tid < 196) {
        float a[ROWS];
        float bi = eb[tid];
#pragma unroll
        for (int r = 0; r < ROWS; ++r) a[r] = bi;
#pragma unroll 4
        for (int n = 0; n < 196; ++n) {
            float ev = eT[(size_t)n * 196 + tid];
#pragma unroll
            for (int r = 0; r < ROWS; ++r) a[r] += ls[r][n] * ev;
        }
#pragma unroll
        for (int r = 0; r < ROWS; ++r) {
            float q = fmaxf(a[r], 0.f);
            qout[((size_t)(b * R + i0 + r)) * 196 + tid] = q;
            qT[((size_t)b * 196 + tid) * R + i0 + r] = q;
        }
    }
}

// ---------------- fused cross-attention, multi-row, de-diverged ------------
template <int ROWS, int RA, int RB>
__global__ void k_attrow_t(const float* __restrict__ own, const float* __restrict__ ownT,
                           const float* __restrict__ oth, const float* __restrict__ othT,
                           const float* __restrict__ wAT, const float* __restrict__ bA,
                           const float* __restrict__ wBT, const float* __restrict__ bB,
                           const float* __restrict__ lnres, const float* __restrict__ res2,
                           float* __restrict__ feat, int cbase) {
    __shared__ float buf1[ROWS][196];      // qs -> fA
    __shared__ float sc[ROWS][176];        // scores -> probs (RA+RB=173)
    __shared__ float fB[ROWS][196];
    const int i0 = blockIdx.x * ROWS, b = blockIdx.y;
    const int tid = threadIdx.x;
    const int wv = tid >> 6, lane = tid & 63;
    const float* ownb = own + (size_t)b * RA * 196;
    const float* othb = oth + (size_t)b * RB * 196;
    for (int idx = tid; idx < ROWS * 196; idx += 256) {
        int r = idx / 196, n = idx - r * 196;
        buf1[r][n] = ownb[(size_t)(i0 + r) * 196 + n];
    }
    __syncthreads();
    {
        const bool act = tid < RA + RB;
        const float* ptr = nullptr;
        int stride = 1;
        if (act) {
            if (tid < RA) { ptr = ownT + (size_t)b * 196 * RA + tid; stride = RA; }
            else          { ptr = othT + (size_t)b * 196 * RB + (tid - RA); stride = RB; }
        }
        if (act) {
            float a[ROWS];
#pragma unroll
            for (int r = 0; r < ROWS; ++r) a[r] = 0.f;
#pragma unroll 4
            for (int n = 0; n < 196; ++n) {
                float kv = ptr[(size_t)n * stride];
#pragma unroll
                for (int r = 0; r < ROWS; ++r) a[r] += buf1[r][n] * kv;
            }
#pragma unroll
            for (int r = 0; r < ROWS; ++r) sc[r][tid] = a[r];
        }
    }
    __syncthreads();
    for (int k = 0;; ++k) {
        int r = wv + 4 * k;
        if (r >= ROWS) break;
        softseg(&sc[r][0], RA, lane);
        softseg(&sc[r][RA], RB, lane);
    }
    __syncthreads();
    if (tid < 196) {
        float a[ROWS];
#pragma unroll
        for (int r = 0; r < ROWS; ++r) a[r] = 0.f;
#pragma unroll 4
        for (int j = 0; j < RA; ++j) {
            float v = ownb[(size_t)j * 196 + tid];
#pragma unroll
            for (int r = 0; r < ROWS; ++r) a[r] += sc[r][j] * v;
        }
        float c[ROWS];
#pragma unroll
        for (int r = 0; r < ROWS; ++r) c[r] = 0.f;
#pragma unroll 4
        for (int j = 0; j < RB; ++j) {
            float v = othb[(size_t)j * 196 + tid];
#pragma unroll
            for (int r = 0; r < ROWS; ++r) c[r] += sc[r][RA + j] * v;
        }
#pragma unroll
        for (int r = 0; r < ROWS; ++r) { buf1[r][tid] = a[r]; fB[r][tid] = c[r]; }
    }
    __syncthreads();
    if (tid < 196) {
        float a[ROWS];
        float bb = bA[tid] + bB[tid];
#pragma unroll
        for (int r = 0; r < ROWS; ++r) {
            size_t rr = ((size_t)(b * RA + i0 + r)) * 196 + tid;
            a[r] = bb + lnres[rr] + res2[rr];
        }
#pragma unroll 4
        for (int n = 0; n < 196; ++n) {
            float wa = wAT[(size_t)n * 196 + tid];
            float wb = wBT[(size_t)n * 196 + tid];
#pragma unroll
            for (int r = 0; r < ROWS; ++r) a[r] += buf1[r][n] * wa + fB[r][n] * wb;
        }
#pragma unroll
        for (int r = 0; r < ROWS; ++r)
            feat[((size_t)(b * 173 + cbase + i0 + r)) * 196 + tid] = a[r];
    }
}

// ---------------- 1x1 conv, multi-row; RES=0 writes qT, RES=1 res+rowsum ----
template <int RES, int ROWS>
__global__ void k_conv1x1_t(const float* __restrict__ x, const float* __restrict__ w,
                            const float* __restrict__ bias, const float* __restrict__ res,
                            float* __restrict__ outp, float* __restrict__ aux) {
    __shared__ float wsm[ROWS][173];
    __shared__ float vals[ROWS][200];
    const int o0 = blockIdx.x * ROWS, b = blockIdx.y;
    const int tid = threadIdx.x;
    const int nv = (173 - o0 < ROWS) ? (173 - o0) : ROWS;
    for (int idx = tid; idx < nv * 173; idx += 256) {
        int r = idx / 173, c = idx - r * 173;
        wsm[r][c] = w[(size_t)(o0 + r) * 173 + c];
    }
    __syncthreads();
    if (tid < 196) {
        float a[ROWS];
#pragma unroll
        for (int r = 0; r < ROWS; ++r) a[r] = (r < nv) ? bias[o0 + r] : 0.f;
#pragma unroll 4
        for (int c = 0; c < 173; ++c) {
            float xv = x[((size_t)(b * 173 + c)) * 196 + tid];
#pragma unroll
            for (int r = 0; r < ROWS; ++r) a[r] += wsm[r][c] * xv;
        }
#pragma unroll
        for (int r = 0; r < ROWS; ++r) {
            if (r < nv) {
                float v = fmaxf(a[r], 0.f);
                size_t rr = ((size_t)(b * 173 + o0 + r)) * 196 + tid;
                if (RES) v += res[rr];
                outp[rr] = v;
                if (!RES) aux[((size_t)b * 196 + tid) * 173 + o0 + r] = v;
                if (RES) vals[r][tid] = v;
            }
        }
    }
    if (RES) {
        __syncthreads();
        int wv = tid >> 6, lane = tid & 63;
        for (int k = 0;; ++k) {
            int r = wv + 4 * k;
            if (r >= nv) break;
            float s = 0.f;
            for (int j = lane; j < 196; j += 64) s += vals[r][j];
            for (int sh = 32; sh; sh >>= 1) s += __shfl_xor(s, sh);
            if (lane == 0) aux[(size_t)b * 173 + o0 + r] = s;
        }
    }
}

// ---------------- CMSA attention (multi-row, writes A^T) ----------------
template <int ROWS>
__global__ void k_cmsa_att_t(const float* __restrict__ q, const float* __restrict__ qT,
                             float* __restrict__ AT) {
    __shared__ float colt[ROWS][176];
    __shared__ float sc[ROWS][200];
    const int i0 = blockIdx.x * ROWS, b = blockIdx.y;
    const int tid = threadIdx.x;
    for (int idx = tid; idx < ROWS * 173; idx += 256) {
        int r = idx / 173, c = idx - r * 173;
        colt[r][c] = qT[((size_t)b * 196 + i0 + r) * 173 + c];
    }
    __syncthreads();
    if (tid < 196) {
        float a[ROWS];
#pragma unroll
        for (int r = 0; r < ROWS; ++r) a[r] = 0.f;
#pragma unroll 4
        for (int c = 0; c < 173; ++c) {
            float qv = q[((size_t)(b * 173 + c)) * 196 + tid];
#pragma unroll
            for (int r = 0; r < ROWS; ++r) a[r] += colt[r][c] * qv;
        }
#pragma unroll
        for (int r = 0; r < ROWS; ++r) sc[r][tid] = a[r];
    }
    __syncthreads();
    int wv = tid >> 6, lane = tid & 63;
    for (int k = 0;; ++k) {
        int r = wv + 4 * k;
        if (r >= ROWS) break;
        softseg(&sc[r][0], 196, lane);
    }
    __syncthreads();
    for (int idx = tid; idx < ROWS * 196; idx += 256) {
        int r = idx / 196, j = idx - r * 196;
        AT[((size_t)b * 196 + j) * 196 + i0 + r] = sc[r][j];
    }
}

// ---------------- CMSA apply (multi-row) ----------------
template <int ROWS>
__global__ void k_cmsa_apply_t(const float* __restrict__ AT, const float* __restrict__ q,
                               float* __restrict__ fea) {
    __shared__ float qsr[ROWS][196];
    const int c0 = blockIdx.x * ROWS, b = blockIdx.y;
    const int tid = threadIdx.x;
    const int nv = (173 - c0 < ROWS) ? (173 - c0) : ROWS;
    for (int idx = tid; idx < nv * 196; idx += 256) {
        int r = idx / 196, n = idx - r * 196;
        qsr[r][n] = q[((size_t)(b * 173 + c0 + r)) * 196 + n];
    }
    __syncthreads();
    if (tid < 196) {
        float a[ROWS];
#pragma unroll
        for (int r = 0; r < ROWS; ++r) a[r] = 0.f;
        const float* at = AT + (size_t)b * 196 * 196 + tid;
#pragma unroll 4
        for (int j = 0; j < 196; ++j) {
            float av = at[(size_t)j * 196];
#pragma unroll
            for (int r = 0; r < ROWS; ++r) a[r] += av * qsr[r][j];
        }
#pragma unroll
        for (int r = 0; r < ROWS; ++r)
            if (r < nv) fea[((size_t)(b * 173 + c0 + r)) * 196 + tid] = a[r];
    }
}

// ---------------- final classifier ----------------
__global__ void k_finale(const float* __restrict__ toh, const float* __restrict__ tnm,
                         const float* __restrict__ rowsum, const float* __restrict__ cls_w,
                         const float* __restrict__ cls_b, float* __restrict__ out) {
    int b = blockIdx.x;
    __shared__ float r1[4], r2[4];
    int tid = threadIdx.x;
    float a = (tid < 196) ? toh[b * 196 + tid] : 0.f;
    float c = (tid < 196) ? tnm[b * 196 + tid] : 0.f;
    for (int sh = 32; sh; sh >>= 1) { a += __shfl_xor(a, sh); c += __shfl_xor(c, sh); }
    if ((tid & 63) == 0) { r1[tid >> 6] = a; r2[tid >> 6] = c; }
    __syncthreads();
    if (tid < 2) {
        float soh = r1[0] + r1[1] + r1[2] + r1[3];
        float snm = r2[0] + r2[1] + r2[2] + r2[3];
        const float* wrow = &cls_w[tid * 218];
        float acc = cls_b[tid];
        float w1 = 0.f, w2 = 0.f;
        for (int k = 0; k < 30; ++k) w1 += wrow[k];
        for (int k = 30; k < 45; ++k) w2 += wrow[k];
        acc += soh * w1 + snm * w2;
        for (int k = 0; k < 173; ++k) acc += wrow[45 + k] * rowsum[(size_t)b * 173 + k];
        out[b * 2 + tid] = acc;
    }
}

// ---------------------------------------------------------------------------
extern "C" void kernel_launch(void* const* d_in, const int* in_sizes, int n_in,
                              void* d_out, int out_size, void* d_ws, size_t ws_size,
                              hipStream_t stream) {
    const float* x      = (const float*)d_in[0];
    const float* oneHot = (const float*)d_in[1];
    const float* num    = (const float*)d_in[2];
    const float* c1_w1  = (const float*)d_in[3];
    const float* c1_g1  = (const float*)d_in[5];
    const float* c1_be1 = (const float*)d_in[6];
    const float* c1_w2  = (const float*)d_in[7];
    const float* c1_g2  = (const float*)d_in[9];
    const float* c1_be2 = (const float*)d_in[10];
    const float* oh_w   = (const float*)d_in[11];
    const float* oh_b   = (const float*)d_in[12];
    const float* oh_g   = (const float*)d_in[13];
    const float* oh_be  = (const float*)d_in[14];
    const float* nm_w   = (const float*)d_in[15];
    const float* nm_b   = (const float*)d_in[16];
    const float* nm_g   = (const float*)d_in[17];
    const float* nm_be  = (const float*)d_in[18];
    const float* gm1_w  = (const float*)d_in[19];
    const float* gm1_b  = (const float*)d_in[20];
    const float* gm2_w  = (const float*)d_in[21];
    const float* gm2_b  = (const float*)d_in[22];
    const float* ln1_g  = (const float*)d_in[23];
    const float* ln1_b  = (const float*)d_in[24];
    const float* ln2_g  = (const float*)d_in[25];
    const float* ln2_b  = (const float*)d_in[26];
    const float* e1_w   = (const float*)d_in[27];
    const float* e1_b   = (const float*)d_in[28];
    const float* e2_w   = (const float*)d_in[29];
    const float* e2_b   = (const float*)d_in[30];
    const float* f1_w   = (const float*)d_in[31];
    const float* f1_b   = (const float*)d_in[32];
    const float* f2_w   = (const float*)d_in[33];
    const float* f2_b   = (const float*)d_in[34];
    const float* f3_w   = (const float*)d_in[35];
    const float* f3_b   = (const float*)d_in[36];
    const float* f4_w   = (const float*)d_in[37];
    const float* f4_b   = (const float*)d_in[38];
    const float* cm_w   = (const float*)d_in[39];
    const float* cm_b   = (const float*)d_in[40];
    const float* cmf_w  = (const float*)d_in[41];
    const float* cmf_b  = (const float*)d_in[42];
    const float* cls_w  = (const float*)d_in[43];
    const float* cls_b  = (const float*)d_in[44];
    float* out = (float*)d_out;
    float* W = (float*)d_ws;

    const size_t L = 802816;
    const size_t T = 282240;
    const size_t F3 = 1085056;
    const size_t o_A    = 0;
    const size_t o_B    = L;
    const size_t o_C    = 2 * L;
    const size_t o_part = 3 * L;          // conv partials [3L, 8L) (G<=5)
    const size_t o_iq   = 3 * L;
    const size_t o_tq   = 4 * L;
    const size_t o_t1   = 4 * L + T;
    const size_t o_t3   = 4 * L + 2 * T;
    const size_t o_ln2  = 4 * L + 3 * T;
    const size_t o_toh  = 4 * L + 4 * T;
    const size_t o_tnm  = o_toh + 6272;
    const size_t o_st   = o_tnm + 6272;
    const size_t o_wT   = o_st + 1024;
    const size_t o_feat = o_wT + 8 * 38416;
    const size_t o_q    = o_feat + F3;
    const size_t o_fea  = o_q + F3;
    const size_t o_Acm  = o_fea + F3;     // A^T [32,196,196]; gcn dists earlier
    const size_t o_d1   = o_Acm;
    const size_t o_d2   = o_Acm + 524288;
    // conv-phase-only buffers (chunk-major bf16):
    const size_t o_xt1 = 9 * L;                       // 32*5*208*72/2 = 1,198,080 floats
    const size_t o_xt2 = o_xt1 + 1198080;             // 32*2*208*72/2 =   479,232
    const size_t o_wp1 = o_xt2 + 479232;              // 27*128*320/2  =   552,960
    const size_t o_wp2 = o_wp1 + 552960;              // 27*128*128/2  =   221,184
    const size_t o_tr  = o_wp2 + 221184;              // = 9,676,800
    const size_t o_rs  = o_tr + F3;                   // rowsum 32*173

    float* part = W + o_part;
    unsigned short* xt1 = (unsigned short*)(W + o_xt1);
    unsigned short* xt2 = (unsigned short*)(W + o_xt2);
    unsigned short* wp1 = (unsigned short*)(W + o_wp1);
    unsigned short* wp2 = (unsigned short*)(W + o_wp2);
    float* gm1T = W + o_wT + 0 * 38416;
    float* gm2T = W + o_wT + 1 * 38416;
    float* e1T  = W + o_wT + 2 * 38416;
    float* e2T  = W + o_wT + 3 * 38416;
    float* f1T  = W + o_wT + 4 * 38416;
    float* f2T  = W + o_wT + 5 * 38416;
    float* f3T  = W + o_wT + 6 * 38416;
    float* f4T  = W + o_wT + 7 * 38416;

    // ---- conv prep ----
    k_wpack<<<(27 * 128 * 40 + 255) / 256, 256, 0, stream>>>(c1_w1, wp1, 320);
    k_wpack<<<(27 * 128 * 16 + 255) / 256, 256, 0, stream>>>(c1_w2, wp2, 128);
    k_xt_c<<<dim3((5 * 208 * 36 + 255) / 256, 32), 256, 0, stream>>>(x, xt1, 320, 5);

    // ---- conv1: 5 chunks x 2 nh(NT=4) x 2 mh -> 640 blocks; BN also emits
    //      conv2's chunk-major bf16 input (xt2) ----
    k_convchunk4<320, 5, 4, 2><<<dim3(20, 32), 256, 0, stream>>>(xt1, wp1, part);
    k_reduceG<5><<<3136, 256, 0, stream>>>(part, W + o_A, 802816);
    k_bn_stats<<<128, 256, 0, stream>>>(W + o_A, W + o_st, 128);
    k_bn_apply_relu<<<4096, 256, 0, stream>>>(W + o_A, W + o_st, c1_g1, c1_be1,
                                              nullptr, xt2, 128);

    // ---- conv2: 2 chunks x 4 nh(NT=2) x 2 mh -> 512 blocks ----
    k_convchunk4<128, 2, 2, 4><<<dim3(16, 32), 256, 0, stream>>>(xt2, wp2, part);
    k_reduceG<2><<<3136, 256, 0, stream>>>(part, W + o_B, 802816);
    k_bn_stats<<<128, 256, 0, stream>>>(W + o_B, W + o_st + 512, 128);
    k_bn_apply_relu<<<4096, 256, 0, stream>>>(W + o_B, W + o_st + 512, c1_g2, c1_be2,
                                              W + o_tr, nullptr, 128);

    // ---- weight transposes ----
    P8 p8;
    p8.p[0] = gm1_w; p8.p[1] = gm2_w; p8.p[2] = e1_w; p8.p[3] = e2_w;
    p8.p[4] = f1_w;  p8.p[5] = f2_w;  p8.p[6] = f3_w; p8.p[7] = f4_w;
    k_transpose8<<<dim3(196, 8), 256, 0, stream>>>(p8, W + o_wT);

    // ---- catnum / text ----
    k_catnum<<<196, 64, 0, stream>>>(oneHot, 24, oh_w, oh_b, oh_g, oh_be, W + o_toh);
    k_catnum<<<196, 64, 0, stream>>>(num, 11, nm_w, nm_b, nm_g, nm_be, W + o_tnm);
    k_textbuild<<<32 * 45, 256, 0, stream>>>(W + o_toh, W + o_tnm, W + o_t1, W + o_tr + L);

    // ---- GCN img ----
    k_gcn_dist_t<128, 4><<<dim3(32, 32), 256, 0, stream>>>(W + o_B, W + o_tr, W + o_d1);
    k_gcn_spmmfin_t<128, 4><<<dim3(32, 32), 256, 0, stream>>>(W + o_d1, W + o_B, gm1T,
                                                              gm1_b, W + o_C);
    // ---- GCN text ----
    k_gcn_dist_t<45, 3><<<dim3(15, 32), 256, 0, stream>>>(W + o_t1, W + o_tr + L, W + o_d2);
    k_gcn_spmmfin_t<45, 3><<<dim3(15, 32), 256, 0, stream>>>(W + o_d2, W + o_t1, gm2T,
                                                             gm2_b, W + o_t3);

    // ---- LN + q projections ----
    k_lnlin_t<128, 4><<<dim3(32, 32), 256, 0, stream>>>(W + o_C, ln1_g, ln1_b, e1T, e1_b,
                                                        W + o_B, W + o_iq, W + o_tr);
    k_lnlin_t<45, 3><<<dim3(15, 32), 256, 0, stream>>>(W + o_t3, ln2_g, ln2_b, e2T, e2_b,
                                                       W + o_ln2, W + o_tq, W + o_tr + L);

    // ---- cross-attention -> feat ----
    k_attrow_t<4, 128, 45><<<dim3(32, 32), 256, 0, stream>>>(
        W + o_iq, W + o_tr, W + o_tq, W + o_tr + L,
        f1T, f1_b, f3T, f3_b, W + o_B, W + o_C, W + o_feat, 0);
    k_attrow_t<3, 45, 128><<<dim3(15, 32), 256, 0, stream>>>(
        W + o_tq, W + o_tr + L, W + o_iq, W + o_tr,
        f2T, f2_b, f4T, f4_b, W + o_ln2, W + o_t3, W + o_feat, 128);

    // ---- CMSA ----
    k_conv1x1_t<0, 4><<<dim3(44, 32), 256, 0, stream>>>(W + o_feat, cm_w, cm_b, nullptr,
                                                        W + o_q, W + o_tr);
    k_cmsa_att_t<4><<<dim3(49, 32), 256, 0, stream>>>(W + o_q, W + o_tr, W + o_Acm);
    k_cmsa_apply_t<4><<<dim3(44, 32), 256, 0, stream>>>(W + o_Acm, W + o_q, W + o_fea);
    k_conv1x1_t<1, 4><<<dim3(44, 32), 256, 0, stream>>>(W + o_fea, cmf_w, cmf_b, W + o_feat,
                                                        W + o_q, W + o_rs);

    // ---- final classifier ----
    k_finale<<<32, 256, 0, stream>>>(W + o_toh, W + o_tnm, W + o_rs, cls_w, cls_b, out);
}

// Round 14
// 467.057 us; speedup vs baseline: 1.2063x; 1.0752x over previous
//
#include <hip/hip_runtime.h>
#include <hip/hip_bf16.h>

// ---------------------------------------------------------------------------
// mv3Dunet_down_text_cmsa forward. Round 14: round-13 CMSA-MFMA retry with
// fixed workspace layout (r13 aliased pbf/qtb and gcn dists -> absmax 3.8e7)
// and conv1x1 biases restored in the GEMM epilogues.
// ---------------------------------------------------------------------------

using bf16x8 = __attribute__((ext_vector_type(8))) short;
using f32x4  = __attribute__((ext_vector_type(4))) float;

typedef const __attribute__((address_space(1))) void gas_void;
typedef __attribute__((address_space(3))) void las_void;

__device__ __forceinline__ unsigned short f2bf(float f) {
    unsigned int u = __float_as_uint(f);
    u += 0x7FFFu + ((u >> 16) & 1u);
    return (unsigned short)(u >> 16);
}

__device__ __forceinline__ void softseg(float* s, int len, int lane) {
    float m = -3.4e38f;
    for (int j = lane; j < len; j += 64) m = fmaxf(m, s[j]);
    for (int sh = 32; sh; sh >>= 1) m = fmaxf(m, __shfl_xor(m, sh));
    float sum = 0.f;
    for (int j = lane; j < len; j += 64) { float e = expf(s[j] - m); s[j] = e; sum += e; }
    for (int sh = 32; sh; sh >>= 1) sum += __shfl_xor(sum, sh);
    float inv = 1.f / sum;
    for (int j = lane; j < len; j += 64) s[j] *= inv;
}

// ---------------- zero helper ----------------
__global__ void k_zero4(float4* __restrict__ p, int n4) {
    int i = blockIdx.x * 256 + threadIdx.x;
    if (i < n4) p[i] = (float4){0.f, 0.f, 0.f, 0.f};
}

// ---------------- X -> chunk-major bf16: xt[b][g][208][72] ----------------
__global__ void k_xt_c(const float* __restrict__ x, unsigned short* __restrict__ xt,
                       int IC, int G) {
    int b = blockIdx.y;
    int tot = G * 208 * 36;
    int idx = blockIdx.x * 256 + threadIdx.x;
    if (idx >= tot) return;
    int g = idx / (208 * 36); int r = idx - g * 208 * 36;
    int s = r / 36, cp = r - s * 36;
    int cc = cp * 2;
    int ic = g * 64 + cc;
    unsigned int lo = 0, hi = 0;
    if (s < 196 && cc < 64 && ic < IC)         lo = f2bf(x[((size_t)b * IC + ic) * 196 + s]);
    if (s < 196 && cc + 1 < 64 && ic + 1 < IC) hi = f2bf(x[((size_t)b * IC + ic + 1) * 196 + s]);
    ((unsigned int*)xt)[(size_t)b * tot + idx] = lo | (hi << 16);
}

// ---------------- weight pack: w[oc][ic][27] f32 -> wp[t][oc][ic] bf16 ------
__global__ void k_wpack(const float* __restrict__ w, unsigned short* __restrict__ wp,
                        int IC) {
    int nc = IC >> 3;
    int idx = blockIdx.x * 256 + threadIdx.x;
    if (idx >= 27 * 128 * nc) return;
    int c = idx % nc; int r = idx / nc; int oc = r & 127; int t = r >> 7;
    const float* ws = w + ((size_t)oc * IC + c * 8) * 27 + t;
    unsigned int o0 = f2bf(ws[0])   | ((unsigned int)f2bf(ws[27])  << 16);
    unsigned int o1 = f2bf(ws[54])  | ((unsigned int)f2bf(ws[81])  << 16);
    unsigned int o2 = f2bf(ws[108]) | ((unsigned int)f2bf(ws[135]) << 16);
    unsigned int o3 = f2bf(ws[162]) | ((unsigned int)f2bf(ws[189]) << 16);
    uint4 v; v.x = o0; v.y = o1; v.z = o2; v.w = o3;
    ((uint4*)wp)[idx] = v;
}

// ---------------- pack 173x173 f32 -> [176][192] bf16 zero-padded -----------
__global__ void k_w173(const float* __restrict__ w, unsigned short* __restrict__ wb) {
    int idx = blockIdx.x * 256 + threadIdx.x;
    if (idx >= 176 * 192) return;
    int oc = idx / 192, c = idx - oc * 192;
    wb[idx] = (oc < 173 && c < 173) ? f2bf(w[(size_t)oc * 173 + c]) : (unsigned short)0;
}

// ---------------- MFMA conv (round-12, validated) ----------------
template <int IC, int G, int NT, int NH>
__global__ __launch_bounds__(256, 3) void k_convchunk4(
    const unsigned short* __restrict__ xt, const unsigned short* __restrict__ wp,
    float* __restrict__ part) {
    __shared__ unsigned short xs[208 * 72];
    __shared__ char bbuf[2][NT * 2048];
    const int tid = threadIdx.x;
    const int bx = blockIdx.x, b = blockIdx.y;
    const int mh = bx & 1;
    const int nh = (bx >> 1) % NH;
    const int g  = (bx >> 1) / NH;
    const int w = tid >> 6, l = tid & 63;

    {
        const bf16x8* s8 = (const bf16x8*)(xt + ((size_t)b * G + g) * (208 * 72));
        bf16x8* d8 = (bf16x8*)xs;
        for (int c = tid; c < 208 * 72 / 8; c += 256) d8[c] = s8[c];
    }

    const char* wslice = (const char*)wp +
                         ((size_t)(nh * NT * 16) * IC + (size_t)g * 64) * 2;
    auto stageB = [&](int t) {
        char* dst = &bbuf[t & 1][w * (NT * 512)];
        const char* wt_ = wslice + (size_t)t * 128 * IC * 2;
#pragma unroll
        for (int c = 0; c < NT / 2; ++c) {
            int q = w * (NT * 512) + c * 1024 + l * 16;
            int row = q >> 7, col = q & 127;
            int scol = col ^ ((row & 7) << 4);
            gas_void* src = (gas_void*)(wt_ + (size_t)row * IC * 2 + scol);
            __builtin_amdgcn_global_load_lds(src, (las_void*)(dst + c * 1024),
                                             16, 0, 0);
        }
    };

    const int lane = tid & 63;
    const int a = lane & 15, kg = lane >> 4;

    int md[2], mhh[2], mw[2];
#pragma unroll
    for (int i = 0; i < 2; ++i) {
        int m = (mh * 8 + (tid >> 6) * 2 + i) * 16 + a;
        md[i] = m / 49; int rr = m - md[i] * 49;
        mhh[i] = rr / 7; mw[i] = rr - mhh[i] * 7;
    }

    f32x4 acc[2][NT];
#pragma unroll
    for (int i = 0; i < 2; ++i)
#pragma unroll
        for (int nt = 0; nt < NT; ++nt) acc[i][nt] = (f32x4){0.f, 0.f, 0.f, 0.f};

    const bf16x8 zv = {0, 0, 0, 0, 0, 0, 0, 0};

    stageB(0);
    __syncthreads();

    for (int t = 0; t < 27; ++t) {
        if (t < 26) stageB(t + 1);
        const int kd = t / 9, kh = (t / 3) % 3, kw = t % 3;
        int rsrc[2]; bool ok[2];
#pragma unroll
        for (int i = 0; i < 2; ++i) {
            int d2 = md[i] + kd - 1, h2 = mhh[i] + kh - 1, w2 = mw[i] + kw - 1;
            ok[i] = ((unsigned)d2 < 4u) & ((unsigned)h2 < 7u) & ((unsigned)w2 < 7u);
            rsrc[i] = ok[i] ? (d2 * 49 + h2 * 7 + w2) : 0;
        }
        bf16x8 A[2][2];
#pragma unroll
        for (int kk = 0; kk < 2; ++kk)
#pragma unroll
            for (int i = 0; i < 2; ++i) {
                bf16x8 v = *(const bf16x8*)(xs + rsrc[i] * 72 + kk * 32 + kg * 8);
                A[kk][i] = ok[i] ? v : zv;
            }
        const char* bb = &bbuf[t & 1][0];
#pragma unroll
        for (int kk = 0; kk < 2; ++kk)
#pragma unroll
            for (int nt = 0; nt < NT; ++nt) {
                int row = nt * 16 + a;
                int cb = (kk * 64 + kg * 16) ^ ((row & 7) << 4);
                bf16x8 B = *(const bf16x8*)(bb + row * 128 + cb);
#pragma unroll
                for (int i = 0; i < 2; ++i)
                    acc[i][nt] = __builtin_amdgcn_mfma_f32_16x16x32_bf16(
                        A[kk][i], B, acc[i][nt], 0, 0, 0);
            }
        __syncthreads();
    }

    float* dst = part + ((size_t)g * 32 + b) * (128 * 196);
#pragma unroll
    for (int i = 0; i < 2; ++i) {
        int m0 = (mh * 8 + (tid >> 6) * 2 + i) * 16 + kg * 4;
        if (m0 < 196) {
#pragma unroll
            for (int nt = 0; nt < NT; ++nt) {
                int oc = nh * NT * 16 + nt * 16 + a;
                *(f32x4*)(dst + (size_t)oc * 196 + m0) = acc[i][nt];
            }
        }
    }
}

// sum G partials
template <int G>
__global__ void k_reduceG(const float* __restrict__ part, float* __restrict__ y, int n) {
    int i = blockIdx.x * blockDim.x + threadIdx.x;
    if (i < n) {
        float s = 0.f;
#pragma unroll
        for (int g = 0; g < G; ++g) s += part[(size_t)g * n + i];
        y[i] = s;
    }
}

// ---------------- generic batched MFMA GEMM (CMSA) ----------------
// EPI 0: q=relu(.+bias) -> qbf[176][224] + qtb[208][192]
// EPI 1: row-softmax -> pbf[208][224]
// EPI 2: plain -> feab[208][192] (transposed)
// EPI 3: relu(.+bias)+resid -> fp32 out
template <int MROWS, int MTILES, int KP, int KK, int EPI>
__global__ __launch_bounds__(256, 2) void k_bgemm(
    const unsigned short* __restrict__ Ab, size_t ABS,
    const unsigned short* __restrict__ Bb, size_t BBS,
    const float* __restrict__ bias,
    unsigned short* __restrict__ p0, unsigned short* __restrict__ p1,
    const float* __restrict__ resid, float* __restrict__ outf) {
    constexpr int KPS = KP + 8;
    __shared__ unsigned short xsA[64 * KPS];
    __shared__ char bbuf[2][208 * 64];
    const int tid = threadIdx.x, bx = blockIdx.x, b = blockIdx.y;
    const int wv = tid >> 6, lane = tid & 63, a = lane & 15, kg = lane >> 4;

    const unsigned short* Abase = Ab + (size_t)b * ABS;
    {
        const int rowu = KP / 2;
        for (int i = tid; i < 64 * rowu; i += 256) {
            int r = i / rowu, cu = i - r * rowu;
            int gr = bx * 64 + r; if (gr > MROWS - 1) gr = MROWS - 1;
            unsigned int v = ((const unsigned int*)(Abase + (size_t)gr * KP))[cu];
            *(unsigned int*)&xsA[r * KPS + cu * 2] = v;
        }
    }
    const char* Bbase = (const char*)(Bb + (size_t)b * BBS);
    auto stageB = [&](int kk) {
        char* dst0 = &bbuf[kk & 1][0];
#pragma unroll
        for (int c = 0; c < 4; ++c) {
            int idx = tid + c * 256;
            if (idx < 832) {
                int row = idx >> 2, u = idx & 3;
                gas_void* src = (gas_void*)(Bbase + (size_t)row * (KP * 2) +
                                            kk * 64 + u * 16);
                __builtin_amdgcn_global_load_lds(src, (las_void*)(dst0 + (size_t)idx * 16),
                                                 16, 0, 0);
            }
        }
    };

    int mt = bx * 4 + wv; if (mt > MTILES - 1) mt = MTILES - 1;
    const int arow = mt * 16 + a - bx * 64;

    f32x4 acc[13];
#pragma unroll
    for (int nt = 0; nt < 13; ++nt) acc[nt] = (f32x4){0.f, 0.f, 0.f, 0.f};

    stageB(0);
    __syncthreads();
    for (int kk = 0; kk < KK; ++kk) {
        if (kk + 1 < KK) stageB(kk + 1);
        bf16x8 Af = *(const bf16x8*)&xsA[arow * KPS + kk * 32 + kg * 8];
        const char* bb = &bbuf[kk & 1][0];
#pragma unroll
        for (int nt = 0; nt < 13; ++nt) {
            int brow = nt * 16 + a;
            bf16x8 Bf = *(const bf16x8*)(bb + brow * 64 + kg * 16);
            acc[nt] = __builtin_amdgcn_mfma_f32_16x16x32_bf16(Af, Bf, acc[nt], 0, 0, 0);
        }
        __syncthreads();
    }

    const int mbase = mt * 16 + kg * 4;
    if (EPI == 0) {
#pragma unroll
        for (int nt = 0; nt < 13; ++nt) {
            int col = nt * 16 + a;
            if (col < 196) {
#pragma unroll
                for (int j = 0; j < 4; ++j) {
                    int row = mbase + j;
                    if (row < 173) {
                        unsigned short h = f2bf(fmaxf(acc[nt][j] + bias[row], 0.f));
                        p0[((size_t)b * 176 + row) * 224 + col] = h;
                        p1[((size_t)b * 208 + col) * 192 + row] = h;
                    }
                }
            }
        }
    } else if (EPI == 1) {
#pragma unroll
        for (int j = 0; j < 4; ++j) {
            int row = mbase + j;
            float m = -3.4e38f;
#pragma unroll
            for (int nt = 0; nt < 13; ++nt) {
                int col = nt * 16 + a;
                float s = (col < 196) ? acc[nt][j] : -3.4e38f;
                m = fmaxf(m, s);
            }
            for (int msk = 1; msk < 16; msk <<= 1) m = fmaxf(m, __shfl_xor(m, msk));
            float e[13]; float sum = 0.f;
#pragma unroll
            for (int nt = 0; nt < 13; ++nt) {
                int col = nt * 16 + a;
                float v = (col < 196) ? expf(acc[nt][j] - m) : 0.f;
                e[nt] = v; sum += v;
            }
            for (int msk = 1; msk < 16; msk <<= 1) sum += __shfl_xor(sum, msk);
            float inv = 1.f / sum;
            if (row < 196) {
#pragma unroll
                for (int nt = 0; nt < 13; ++nt) {
                    int col = nt * 16 + a;
                    p0[((size_t)b * 208 + row) * 224 + col] = f2bf(e[nt] * inv);
                }
            }
        }
    } else if (EPI == 2) {
#pragma unroll
        for (int nt = 0; nt < 13; ++nt) {
            int col = nt * 16 + a;
#pragma unroll
            for (int j = 0; j < 4; ++j) {
                int row = mbase + j;
                if (row < 173)
                    p0[((size_t)b * 208 + col) * 192 + row] = f2bf(acc[nt][j]);
            }
        }
    } else {
#pragma unroll
        for (int nt = 0; nt < 13; ++nt) {
            int col = nt * 16 + a;
            if (col < 196) {
#pragma unroll
                for (int j = 0; j < 4; ++j) {
                    int row = mbase + j;
                    if (row < 173) {
                        size_t rr = ((size_t)b * 173 + row) * 196 + col;
                        outf[rr] = fmaxf(acc[nt][j] + bias[row], 0.f) + resid[rr];
                    }
                }
            }
        }
    }
}

// ---------------- rowsum for finale ----------------
__global__ void k_rowsum(const float* __restrict__ cms, float* __restrict__ rs) {
    int oc = blockIdx.x, b = blockIdx.y;
    int lane = threadIdx.x;
    const float* p = cms + ((size_t)b * 173 + oc) * 196;
    float s = 0.f;
    for (int j = lane; j < 196; j += 64) s += p[j];
    for (int sh = 32; sh; sh >>= 1) s += __shfl_xor(s, sh);
    if (lane == 0) rs[(size_t)b * 173 + oc] = s;
}

// ---------------- transpose of 8 [196,196] matrices ----------------
struct P8 { const float* p[8]; };
__global__ void k_transpose8(P8 ws_in, float* __restrict__ wt) {
    int i = blockIdx.x, m = blockIdx.y;
    const float* w = ws_in.p[m];
    float* o = wt + (size_t)m * 38416;
    for (int t = threadIdx.x; t < 196; t += blockDim.x)
        o[(size_t)i * 196 + t] = w[(size_t)t * 196 + i];
}

// ---------------- BN ----------------
__global__ void k_bn_stats(const float* __restrict__ y, float* __restrict__ stats,
                           int C) {
    int ch = blockIdx.x; int tid = threadIdx.x;
    float s = 0.f, s2 = 0.f;
    for (int b = 0; b < 32; ++b) {
        const float* p = &y[(size_t)(b * C + ch) * 196];
        for (int i = tid; i < 196; i += 256) { float v = p[i]; s += v; s2 += v * v; }
    }
    __shared__ float r1[4], r2[4];
    for (int sh = 32; sh; sh >>= 1) { s += __shfl_xor(s, sh); s2 += __shfl_xor(s2, sh); }
    if ((tid & 63) == 0) { r1[tid >> 6] = s; r2[tid >> 6] = s2; }
    __syncthreads();
    if (tid == 0) {
        float S = r1[0] + r1[1] + r1[2] + r1[3];
        float S2 = r2[0] + r2[1] + r2[2] + r2[3];
        float m = S / 6272.f;
        float v = S2 / 6272.f - m * m;
        stats[2 * ch] = m;
        stats[2 * ch + 1] = rsqrtf(v + 1e-5f);
    }
}

__global__ void k_bn_apply_relu(float* __restrict__ y, const float* __restrict__ stats,
                                const float* __restrict__ g, const float* __restrict__ be,
                                float* __restrict__ fT, unsigned short* __restrict__ xtc,
                                int C) {
    int idx = blockIdx.x;
    int ch = idx % C, b = idx / C;
    int s = threadIdx.x;
    if (s < 196) {
        float m = stats[2 * ch], r = stats[2 * ch + 1];
        float v = y[(size_t)idx * 196 + s];
        float o = fmaxf((v - m) * r * g[ch] + be[ch], 0.f);
        y[(size_t)idx * 196 + s] = o;
        if (fT) fT[((size_t)b * 196 + s) * C + ch] = o;
        if (xtc) {
            int G = C >> 6, gch = ch >> 6, cc = ch & 63;
            xtc[(((size_t)b * G + gch) * 208 + s) * 72 + cc] = f2bf(o);
        }
    }
}

// ---------------- catnum ----------------
__global__ void k_catnum(const float* __restrict__ inp, int A,
                         const float* __restrict__ w, const float* __restrict__ bias,
                         const float* __restrict__ g, const float* __restrict__ be,
                         float* __restrict__ outv) {
    int j = blockIdx.x;
    int lane = threadIdx.x;
    float v = 0.f;
    if (lane < 32) {
        v = bias[j];
        for (int k = 0; k < A; ++k) v += inp[lane * A + k] * w[j * A + k];
    }
    float s = (lane < 32) ? v : 0.f;
    float s2 = (lane < 32) ? v * v : 0.f;
    for (int m = 16; m; m >>= 1) { s += __shfl_xor(s, m, 32); s2 += __shfl_xor(s2, m, 32); }
    if (lane < 32) {
        float mean = s / 32.f;
        float var = s2 / 32.f - mean * mean;
        float rstd = rsqrtf(var + 1e-5f);
        float t = (v - mean) * rstd * g[j] + be[j];
        t = t / (1.f + expf(-t));
        outv[lane * 196 + j] = t;
    }
}

__global__ void k_textbuild(const float* __restrict__ toh, const float* __restrict__ tnm,
                            float* __restrict__ text, float* __restrict__ textT) {
    int idx = blockIdx.x;
    int b = idx / 45, c = idx - b * 45;
    int s = threadIdx.x;
    if (s < 196) {
        float v = (c < 30) ? toh[b * 196 + s] : tnm[b * 196 + s];
        text[(size_t)idx * 196 + s] = v;
        textT[((size_t)b * 196 + s) * 45 + c] = v;
    }
}

// ---------------- GCN dist (multi-row) ----------------
template <int C, int ROWS>
__global__ void k_gcn_dist_t(const float* __restrict__ f, const float* __restrict__ fT,
                             float* __restrict__ dist) {
    __shared__ float fi[ROWS][196];
    const int i0 = blockIdx.x * ROWS, b = blockIdx.y;
    const int tid = threadIdx.x;
    for (int idx = tid; idx < ROWS * 196; idx += 256) {
        int r = idx / 196, n = idx - r * 196;
        fi[r][n] = f[((size_t)(b * C + i0 + r)) * 196 + n];
    }
    __syncthreads();
    if (tid < C) {
        const float* ft = fT + (size_t)b * 196 * C + tid;
        float a[ROWS];
#pragma unroll
        for (int r = 0; r < ROWS; ++r) a[r] = 0.f;
#pragma unroll 4
        for (int n = 0; n < 196; ++n) {
            float v = ft[(size_t)n * C];
#pragma unroll
            for (int r = 0; r < ROWS; ++r) a[r] += fabsf(fi[r][n] - v);
        }
#pragma unroll
        for (int r = 0; r < ROWS; ++r)
            dist[((size_t)(b * C + i0 + r)) * C + tid] = expf(-a[r]);
    }
}

// ---------------- GCN spmm+fin (multi-row) ----------------
template <int C, int ROWS>
__global__ void k_gcn_spmmfin_t(const float* __restrict__ dist, const float* __restrict__ f,
                                const float* __restrict__ wt, const float* __restrict__ bias,
                                float* __restrict__ outp) {
    __shared__ float ds[ROWS][C];
    __shared__ float ts[ROWS][196];
    const int i0 = blockIdx.x * ROWS, b = blockIdx.y;
    const int tid = threadIdx.x;
    for (int idx = tid; idx < ROWS * C; idx += 256) {
        int r = idx / C, j = idx - r * C;
        ds[r][j] = dist[((size_t)(b * C + i0 + r)) * C + j];
    }
    __syncthreads();
    if (tid < 196) {
        float a[ROWS];
#pragma unroll
        for (int r = 0; r < ROWS; ++r) a[r] = 0.f;
#pragma unroll 4
        for (int j = 0; j < C; ++j) {
            float v = f[((size_t)b * C + j) * 196 + tid];
#pragma unroll
            for (int r = 0; r < ROWS; ++r) a[r] += ds[r][j] * v;
        }
#pragma unroll
        for (int r = 0; r < ROWS; ++r) ts[r][tid] = a[r];
    }
    __syncthreads();
    if (tid < 196) {
        float a[ROWS];
        float bi = bias[tid];
#pragma unroll
        for (int r = 0; r < ROWS; ++r) a[r] = bi;
#pragma unroll 4
        for (int n = 0; n < 196; ++n) {
            float wv = wt[(size_t)n * 196 + tid];
#pragma unroll
            for (int r = 0; r < ROWS; ++r) a[r] += ts[r][n] * wv;
        }
#pragma unroll
        for (int r = 0; r < ROWS; ++r) {
            size_t rr = ((size_t)(b * C + i0 + r)) * 196 + tid;
            outp[rr] = fmaxf(a[r], 0.f) + f[rr];
        }
    }
}

// ---------------- LN + relu(linear), multi-row, dual-layout q ----------------
template <int R, int ROWS>
__global__ void k_lnlin_t(const float* __restrict__ x, const float* __restrict__ g,
                          const float* __restrict__ be, const float* __restrict__ eT,
                          const float* __restrict__ eb, float* __restrict__ lnout,
                          float* __restrict__ qout, float* __restrict__ qT) {
    __shared__ float ls[ROWS][196];
    const int i0 = blockIdx.x * ROWS, b = blockIdx.y;
    const int tid = threadIdx.x;
    const int wv = tid >> 6, lane = tid & 63;
    for (int idx = tid; idx < ROWS * 196; idx += 256) {
        int r = idx / 196, n = idx - r * 196;
        ls[r][n] = x[((size_t)(b * R + i0 + r)) * 196 + n];
    }
    __syncthreads();
    for (int k = 0;; ++k) {
        int r = wv + 4 * k;
        if (r >= ROWS) break;
        float s = 0.f, s2 = 0.f;
        for (int j = lane; j < 196; j += 64) { float v = ls[r][j]; s += v; s2 += v * v; }
        for (int sh = 32; sh; sh >>= 1) { s += __shfl_xor(s, sh); s2 += __shfl_xor(s2, sh); }
        float mean = s / 196.f;
        float var = s2 / 196.f - mean * mean;
        float rstd = rsqrtf(var + 1e-6f);
        size_t rowo = ((size_t)(b * R + i0 + r)) * 196;
        for (int j = lane; j < 196; j += 64) {
            float l = (ls[r][j] - mean) * rstd * g[j] + be[j];
            ls[r][j] = l;
            lnout[rowo + j] = l;
        }
    }
    __syncthreads();
    if (tid < 196) {
        float a[ROWS];
        float bi = eb[tid];
#pragma unroll
        for (int r = 0; r < ROWS; ++r) a[r] = bi;
#pragma unroll 4
        for (int n = 0; n < 196; ++n) {
            float ev = eT[(size_t)n * 196 + tid];
#pragma unroll
            for (int r = 0; r < ROWS; ++r) a[r] += ls[r][n] * ev;
        }
#pragma unroll
        for (int r = 0; r < ROWS; ++r) {
            float q = fmaxf(a[r], 0.f);
            qout[((size_t)(b * R + i0 + r)) * 196 + tid] = q;
            qT[((size_t)b * 196 + tid) * R + i0 + r] = q;
        }
    }
}

// ---------------- fused cross-attention, multi-row (+featT bf16 out) --------
template <int ROWS, int RA, int RB>
__global__ void k_attrow_t(const float* __restrict__ own, const float* __restrict__ ownT,
                           const float* __restrict__ oth, const float* __restrict__ othT,
                           const float* __restrict__ wAT, const float* __restrict__ bA,
                           const float* __restrict__ wBT, const float* __restrict__ bB,
                           const float* __restrict__ lnres, const float* __restrict__ res2,
                           float* __restrict__ feat, unsigned short* __restrict__ ftb,
                           int cbase) {
    __shared__ float buf1[ROWS][196];
    __shared__ float sc[ROWS][176];
    __shared__ float fB[ROWS][196];
    const int i0 = blockIdx.x * ROWS, b = blockIdx.y;
    const int tid = threadIdx.x;
    const int wv = tid >> 6, lane = tid & 63;
    const float* ownb = own + (size_t)b * RA * 196;
    const float* othb = oth + (size_t)b * RB * 196;
    for (int idx = tid; idx < ROWS * 196; idx += 256) {
        int r = idx / 196, n = idx - r * 196;
        buf1[r][n] = ownb[(size_t)(i0 + r) * 196 + n];
    }
    __syncthreads();
    {
        const bool act = tid < RA + RB;
        const float* ptr = nullptr;
        int stride = 1;
        if (act) {
            if (tid < RA) { ptr = ownT + (size_t)b * 196 * RA + tid; stride = RA; }
            else          { ptr = othT + (size_t)b * 196 * RB + (tid - RA); stride = RB; }
        }
        if (act) {
            float a[ROWS];
#pragma unroll
            for (int r = 0; r < ROWS; ++r) a[r] = 0.f;
#pragma unroll 4
            for (int n = 0; n < 196; ++n) {
                float kv = ptr[(size_t)n * stride];
#pragma unroll
                for (int r = 0; r < ROWS; ++r) a[r] += buf1[r][n] * kv;
            }
#pragma unroll
            for (int r = 0; r < ROWS; ++r) sc[r][tid] = a[r];
        }
    }
    __syncthreads();
    for (int k = 0;; ++k) {
        int r = wv + 4 * k;
        if (r >= ROWS) break;
        softseg(&sc[r][0], RA, lane);
        softseg(&sc[r][RA], RB, lane);
    }
    __syncthreads();
    if (tid < 196) {
        float a[ROWS];
#pragma unroll
        for (int r = 0; r < ROWS; ++r) a[r] = 0.f;
#pragma unroll 4
        for (int j = 0; j < RA; ++j) {
            float v = ownb[(size_t)j * 196 + tid];
#pragma unroll
            for (int r = 0; r < ROWS; ++r) a[r] += sc[r][j] * v;
        }
        float c[ROWS];
#pragma unroll
        for (int r = 0; r < ROWS; ++r) c[r] = 0.f;
#pragma unroll 4
        for (int j = 0; j < RB; ++j) {
            float v = othb[(size_t)j * 196 + tid];
#pragma unroll
            for (int r = 0; r < ROWS; ++r) c[r] += sc[r][RA + j] * v;
        }
#pragma unroll
        for (int r = 0; r < ROWS; ++r) { buf1[r][tid] = a[r]; fB[r][tid] = c[r]; }
    }
    __syncthreads();
    if (tid < 196) {
        float a[ROWS];
        float bb = bA[tid] + bB[tid];
#pragma unroll
        for (int r = 0; r < ROWS; ++r) {
            size_t rr = ((size_t)(b * RA + i0 + r)) * 196 + tid;
            a[r] = bb + lnres[rr] + res2[rr];
        }
#pragma unroll 4
        for (int n = 0; n < 196; ++n) {
            float wa = wAT[(size_t)n * 196 + tid];
            float wb = wBT[(size_t)n * 196 + tid];
#pragma unroll
            for (int r = 0; r < ROWS; ++r) a[r] += buf1[r][n] * wa + fB[r][n] * wb;
        }
#pragma unroll
        for (int r = 0; r < ROWS; ++r) {
            feat[((size_t)(b * 173 + cbase + i0 + r)) * 196 + tid] = a[r];
            ftb[((size_t)b * 208 + tid) * 192 + (cbase + i0 + r)] = f2bf(a[r]);
        }
    }
}

// ---------------- final classifier ----------------
__global__ void k_finale(const float* __restrict__ toh, const float* __restrict__ tnm,
                         const float* __restrict__ rowsum, const float* __restrict__ cls_w,
                         const float* __restrict__ cls_b, float* __restrict__ out) {
    int b = blockIdx.x;
    __shared__ float r1[4], r2[4];
    int tid = threadIdx.x;
    float a = (tid < 196) ? toh[b * 196 + tid] : 0.f;
    float c = (tid < 196) ? tnm[b * 196 + tid] : 0.f;
    for (int sh = 32; sh; sh >>= 1) { a += __shfl_xor(a, sh); c += __shfl_xor(c, sh); }
    if ((tid & 63) == 0) { r1[tid >> 6] = a; r2[tid >> 6] = c; }
    __syncthreads();
    if (tid < 2) {
        float soh = r1[0] + r1[1] + r1[2] + r1[3];
        float snm = r2[0] + r2[1] + r2[2] + r2[3];
        const float* wrow = &cls_w[tid * 218];
        float acc = cls_b[tid];
        float w1 = 0.f, w2 = 0.f;
        for (int k = 0; k < 30; ++k) w1 += wrow[k];
        for (int k = 30; k < 45; ++k) w2 += wrow[k];
        acc += soh * w1 + snm * w2;
        for (int k = 0; k < 173; ++k) acc += wrow[45 + k] * rowsum[(size_t)b * 173 + k];
        out[b * 2 + tid] = acc;
    }
}

// ---------------------------------------------------------------------------
extern "C" void kernel_launch(void* const* d_in, const int* in_sizes, int n_in,
                              void* d_out, int out_size, void* d_ws, size_t ws_size,
                              hipStream_t stream) {
    const float* x      = (const float*)d_in[0];
    const float* oneHot = (const float*)d_in[1];
    const float* num    = (const float*)d_in[2];
    const float* c1_w1  = (const float*)d_in[3];
    const float* c1_g1  = (const float*)d_in[5];
    const float* c1_be1 = (const float*)d_in[6];
    const float* c1_w2  = (const float*)d_in[7];
    const float* c1_g2  = (const float*)d_in[9];
    const float* c1_be2 = (const float*)d_in[10];
    const float* oh_w   = (const float*)d_in[11];
    const float* oh_b   = (const float*)d_in[12];
    const float* oh_g   = (const float*)d_in[13];
    const float* oh_be  = (const float*)d_in[14];
    const float* nm_w   = (const float*)d_in[15];
    const float* nm_b   = (const float*)d_in[16];
    const float* nm_g   = (const float*)d_in[17];
    const float* nm_be  = (const float*)d_in[18];
    const float* gm1_w  = (const float*)d_in[19];
    const float* gm1_b  = (const float*)d_in[20];
    const float* gm2_w  = (const float*)d_in[21];
    const float* gm2_b  = (const float*)d_in[22];
    const float* ln1_g  = (const float*)d_in[23];
    const float* ln1_b  = (const float*)d_in[24];
    const float* ln2_g  = (const float*)d_in[25];
    const float* ln2_b  = (const float*)d_in[26];
    const float* e1_w   = (const float*)d_in[27];
    const float* e1_b   = (const float*)d_in[28];
    const float* e2_w   = (const float*)d_in[29];
    const float* e2_b   = (const float*)d_in[30];
    const float* f1_w   = (const float*)d_in[31];
    const float* f1_b   = (const float*)d_in[32];
    const float* f2_w   = (const float*)d_in[33];
    const float* f2_b   = (const float*)d_in[34];
    const float* f3_w   = (const float*)d_in[35];
    const float* f3_b   = (const float*)d_in[36];
    const float* f4_w   = (const float*)d_in[37];
    const float* f4_b   = (const float*)d_in[38];
    const float* cm_w   = (const float*)d_in[39];
    const float* cm_b   = (const float*)d_in[40];
    const float* cmf_w  = (const float*)d_in[41];
    const float* cmf_b  = (const float*)d_in[42];
    const float* cls_w  = (const float*)d_in[43];
    const float* cls_b  = (const float*)d_in[44];
    float* out = (float*)d_out;
    float* W = (float*)d_ws;

    const size_t L = 802816;
    const size_t T = 282240;
    const size_t F3 = 1085056;
    // ---- layout (floats), live ranges verified ----
    const size_t o_A    = 0;
    const size_t o_B    = L;
    const size_t o_C    = 2 * L;
    const size_t o_part = 3 * L;              // conv partials [3L, 8L)
    const size_t o_iq   = 3 * L;
    const size_t o_tq   = 4 * L;
    const size_t o_t1   = 4 * L + T;
    const size_t o_t3   = 4 * L + 2 * T;
    const size_t o_ln2  = 4 * L + 3 * T;
    const size_t o_toh  = 4 * L + 4 * T;      // 4,340,224
    const size_t o_tnm  = o_toh + 6272;
    const size_t o_st   = o_tnm + 6272;
    const size_t o_wT   = o_st + 1024;        // 4,353,792
    const size_t o_feat = o_wT + 8 * 38416;   // 4,661,120
    const size_t o_q    = o_feat + F3;        // 5,746,176
    const size_t o_dd   = o_q + F3;           // 6,831,232: d1/d2 -> pbf -> rs
    const size_t o_d1   = o_dd;               // 524,288
    const size_t o_d2   = o_dd + 524288;      // 64,800
    const size_t o_pbf  = o_dd;               // [32][208][224] bf16 = 745,472 fl
    const size_t o_rs   = o_dd;               // 32*173 (after pbf dead)
    const size_t o_qbf  = o_dd + 745472;      // 7,576,704: [32][176][224] = 630,784
    const size_t o_wcm  = o_qbf + 630784;     // 8,207,488
    const size_t o_wcmf = o_wcm + 16896;      // 8,224,384
    const size_t o_ftb  = o_wcmf + 16896;     // 8,241,280: [32][208][192] = 638,976
    const size_t o_tr   = o_ftb + 638976;     // 8,880,256: fT/qT twins (L+T)
    const size_t o_qtb  = o_tr;               // overlays o_tr (dead after attrow)
    const size_t o_feab = o_qtb + 638976;     // 9,519,232
    // total = o_feab + 638,976 = 10,158,208 floats = 40.6 MB
    // conv scratch (dead after conv2), overlays o_dd..:
    const size_t o_xt1 = o_dd;                // 1,198,080
    const size_t o_xt2 = o_xt1 + 1198080;     // 479,232   (ends 8,508,544 < o_tr)
    const size_t o_wp1 = o_xt2 + 479232;      // 552,960
    const size_t o_wp2 = o_wp1 + 552960;      // 221,184   (ends 9,282,688)

    float* part = W + o_part;
    unsigned short* xt1 = (unsigned short*)(W + o_xt1);
    unsigned short* xt2 = (unsigned short*)(W + o_xt2);
    unsigned short* wp1 = (unsigned short*)(W + o_wp1);
    unsigned short* wp2 = (unsigned short*)(W + o_wp2);
    unsigned short* ftb = (unsigned short*)(W + o_ftb);
    unsigned short* qtb = (unsigned short*)(W + o_qtb);
    unsigned short* feab = (unsigned short*)(W + o_feab);
    unsigned short* qbf = (unsigned short*)(W + o_qbf);
    unsigned short* wcmb = (unsigned short*)(W + o_wcm);
    unsigned short* wcmfb = (unsigned short*)(W + o_wcmf);
    unsigned short* pbf = (unsigned short*)(W + o_pbf);
    float* gm1T = W + o_wT + 0 * 38416;
    float* gm2T = W + o_wT + 1 * 38416;
    float* e1T  = W + o_wT + 2 * 38416;
    float* e2T  = W + o_wT + 3 * 38416;
    float* f1T  = W + o_wT + 4 * 38416;
    float* f2T  = W + o_wT + 5 * 38416;
    float* f3T  = W + o_wT + 6 * 38416;
    float* f4T  = W + o_wT + 7 * 38416;

    // ---- conv prep (conv scratch region) ----
    k_wpack<<<(27 * 128 * 40 + 255) / 256, 256, 0, stream>>>(c1_w1, wp1, 320);
    k_wpack<<<(27 * 128 * 16 + 255) / 256, 256, 0, stream>>>(c1_w2, wp2, 128);
    k_xt_c<<<dim3((5 * 208 * 36 + 255) / 256, 32), 256, 0, stream>>>(x, xt1, 320, 5);

    // ---- conv1 (BN also emits conv2's chunk-major bf16 input xt2) ----
    k_convchunk4<320, 5, 4, 2><<<dim3(20, 32), 256, 0, stream>>>(xt1, wp1, part);
    k_reduceG<5><<<3136, 256, 0, stream>>>(part, W + o_A, 802816);
    k_bn_stats<<<128, 256, 0, stream>>>(W + o_A, W + o_st, 128);
    k_bn_apply_relu<<<4096, 256, 0, stream>>>(W + o_A, W + o_st, c1_g1, c1_be1,
                                              nullptr, xt2, 128);

    // ---- conv2 (BN emits fTimg at o_tr) ----
    k_convchunk4<128, 2, 2, 4><<<dim3(16, 32), 256, 0, stream>>>(xt2, wp2, part);
    k_reduceG<2><<<3136, 256, 0, stream>>>(part, W + o_B, 802816);
    k_bn_stats<<<128, 256, 0, stream>>>(W + o_B, W + o_st + 512, 128);
    k_bn_apply_relu<<<4096, 256, 0, stream>>>(W + o_B, W + o_st + 512, c1_g2, c1_be2,
                                              W + o_tr, nullptr, 128);

    // ---- conv scratch dead: CMSA weight packs + zero ftb/qbf ----
    k_w173<<<(176 * 192 + 255) / 256, 256, 0, stream>>>(cm_w, wcmb);
    k_w173<<<(176 * 192 + 255) / 256, 256, 0, stream>>>(cmf_w, wcmfb);
    k_zero4<<<(638976 / 4 + 255) / 256, 256, 0, stream>>>((float4*)(W + o_ftb), 638976 / 4);
    k_zero4<<<(630784 / 4 + 255) / 256, 256, 0, stream>>>((float4*)(W + o_qbf), 630784 / 4);

    // ---- weight transposes ----
    P8 p8;
    p8.p[0] = gm1_w; p8.p[1] = gm2_w; p8.p[2] = e1_w; p8.p[3] = e2_w;
    p8.p[4] = f1_w;  p8.p[5] = f2_w;  p8.p[6] = f3_w; p8.p[7] = f4_w;
    k_transpose8<<<dim3(196, 8), 256, 0, stream>>>(p8, W + o_wT);

    // ---- catnum / text (fTtxt at o_tr+L) ----
    k_catnum<<<196, 64, 0, stream>>>(oneHot, 24, oh_w, oh_b, oh_g, oh_be, W + o_toh);
    k_catnum<<<196, 64, 0, stream>>>(num, 11, nm_w, nm_b, nm_g, nm_be, W + o_tnm);
    k_textbuild<<<32 * 45, 256, 0, stream>>>(W + o_toh, W + o_tnm, W + o_t1, W + o_tr + L);

    // ---- GCN img / txt (dists in o_dd region) ----
    k_gcn_dist_t<128, 4><<<dim3(32, 32), 256, 0, stream>>>(W + o_B, W + o_tr, W + o_d1);
    k_gcn_spmmfin_t<128, 4><<<dim3(32, 32), 256, 0, stream>>>(W + o_d1, W + o_B, gm1T,
                                                              gm1_b, W + o_C);
    k_gcn_dist_t<45, 3><<<dim3(15, 32), 256, 0, stream>>>(W + o_t1, W + o_tr + L, W + o_d2);
    k_gcn_spmmfin_t<45, 3><<<dim3(15, 32), 256, 0, stream>>>(W + o_d2, W + o_t1, gm2T,
                                                             gm2_b, W + o_t3);

    // dists dead: zero pbf
    k_zero4<<<(745472 / 4 + 255) / 256, 256, 0, stream>>>((float4*)(W + o_pbf), 745472 / 4);

    // ---- LN + q projections (qT overwrites fT twins at o_tr) ----
    k_lnlin_t<128, 4><<<dim3(32, 32), 256, 0, stream>>>(W + o_C, ln1_g, ln1_b, e1T, e1_b,
                                                        W + o_B, W + o_iq, W + o_tr);
    k_lnlin_t<45, 3><<<dim3(15, 32), 256, 0, stream>>>(W + o_t3, ln2_g, ln2_b, e2T, e2_b,
                                                       W + o_ln2, W + o_tq, W + o_tr + L);

    // ---- cross-attention -> feat (fp32) + featT (bf16) ----
    k_attrow_t<4, 128, 45><<<dim3(32, 32), 256, 0, stream>>>(
        W + o_iq, W + o_tr, W + o_tq, W + o_tr + L,
        f1T, f1_b, f3T, f3_b, W + o_B, W + o_C, W + o_feat, ftb, 0);
    k_attrow_t<3, 45, 128><<<dim3(15, 32), 256, 0, stream>>>(
        W + o_tq, W + o_tr + L, W + o_iq, W + o_tr,
        f2T, f2_b, f4T, f4_b, W + o_ln2, W + o_t3, W + o_feat, ftb, 128);

    // o_tr dead: zero qtb + feab (contiguous)
    k_zero4<<<(1277952 / 4 + 255) / 256, 256, 0, stream>>>((float4*)(W + o_qtb),
                                                           1277952 / 4);

    // ---- CMSA via MFMA GEMMs ----
    k_bgemm<176, 11, 192, 6, 0><<<dim3(3, 32), 256, 0, stream>>>(
        wcmb, 0, ftb, (size_t)208 * 192, cm_b, qbf, qtb, nullptr, nullptr);
    k_bgemm<208, 13, 192, 6, 1><<<dim3(4, 32), 256, 0, stream>>>(
        qtb, (size_t)208 * 192, qtb, (size_t)208 * 192, nullptr, pbf, nullptr,
        nullptr, nullptr);
    k_bgemm<176, 11, 224, 7, 2><<<dim3(3, 32), 256, 0, stream>>>(
        qbf, (size_t)176 * 224, pbf, (size_t)208 * 224, nullptr, feab, nullptr,
        nullptr, nullptr);
    k_bgemm<176, 11, 192, 6, 3><<<dim3(3, 32), 256, 0, stream>>>(
        wcmfb, 0, feab, (size_t)208 * 192, cmf_b, nullptr, nullptr,
        W + o_feat, W + o_q);

    // ---- rowsum + final classifier (rs in dead pbf region) ----
    k_rowsum<<<dim3(173, 32), 64, 0, stream>>>(W + o_q, W + o_rs);
    k_finale<<<32, 256, 0, stream>>>(W + o_toh, W + o_tnm, W + o_rs, cls_w, cls_b, out);
}